// Round 1
// baseline (746.650 us; speedup 1.0000x reference)
//
#include <hip/hip_runtime.h>

#define NN   30000
#define NNZE 480000

// ---------------------------------------------------------------------------
// zero workspace accumulators (lK, rK, K2 laid out contiguously)
// ---------------------------------------------------------------------------
__global__ __launch_bounds__(256) void zero_kernel(float* __restrict__ p, int n4) {
    int i = blockIdx.x * blockDim.x + threadIdx.x;
    if (i < n4) ((float4*)p)[i] = make_float4(0.f, 0.f, 0.f, 0.f);
}

// ---------------------------------------------------------------------------
// SpMM D=64: one wave per edge, lane = feature column.
//   lK[rows[e]] += vals[e] * r_feat[cols[e]]
//   rK[cols[e]] += vals[e] * l_feat[rows[e]]
// ---------------------------------------------------------------------------
__global__ __launch_bounds__(256) void spmm64_kernel(
    const int* __restrict__ rows, const int* __restrict__ cols,
    const float* __restrict__ vals,
    const float* __restrict__ lfeat, const float* __restrict__ rfeat,
    float* __restrict__ lK, float* __restrict__ rK)
{
    int e    = (blockIdx.x << 2) + (threadIdx.x >> 6);
    int lane = threadIdx.x & 63;
    if (e >= NNZE) return;
    int   r = rows[e], c = cols[e];
    float v = vals[e];
    atomicAdd(&lK[(size_t)r * 64 + lane], v * rfeat[(size_t)c * 64 + lane]);
    atomicAdd(&rK[(size_t)c * 64 + lane], v * lfeat[(size_t)r * 64 + lane]);
}

// ---------------------------------------------------------------------------
// SpMM D=256: K2[rows[e]] += vals[e] * z1[cols[e]]
// ---------------------------------------------------------------------------
__global__ __launch_bounds__(256) void spmm256_kernel(
    const int* __restrict__ rows, const int* __restrict__ cols,
    const float* __restrict__ vals,
    const float* __restrict__ z1, float* __restrict__ K2)
{
    int e    = (blockIdx.x << 2) + (threadIdx.x >> 6);
    int lane = threadIdx.x & 63;
    if (e >= NNZE) return;
    int   r = rows[e], c = cols[e];
    float v = vals[e];
    const float* src = z1 + (size_t)c * 256;
    float*       dst = K2 + (size_t)r * 256;
#pragma unroll
    for (int j = 0; j < 4; ++j)
        atomicAdd(&dst[j * 64 + lane], v * src[j * 64 + lane]);
}

// ---------------------------------------------------------------------------
// Fused dense: out = relu([A, A.*B] @ [Wa; Wb] + ba + bb)
//   A,B: [NN][D]   Wa,Wb: [D][DOUT_T]   out: [NN][DOUT_T]
// Block: 256 threads, tile 32 rows x 128 cols. K processed in 128-chunks.
// LDS: W chunk 64KB + input-row chunk 16KB = 80KB -> 2 blocks/CU.
// Each thread: 4 rows x 4 cols accumulators (16 FMA per 5 LDS reads).
// ---------------------------------------------------------------------------
template<int D, int DOUT_T>
__global__ __launch_bounds__(256) void dense_kernel(
    const float* __restrict__ A,  const float* __restrict__ B,
    const float* __restrict__ Wa, const float* __restrict__ Wb,
    const float* __restrict__ ba, const float* __restrict__ bb,
    float* __restrict__ out)
{
    __shared__ float sW[128][128];
    __shared__ float sIn[32][128];

    const int t       = threadIdx.x;
    const int rowbase = blockIdx.x * 32;
    const int colbase = blockIdx.y * 128;
    const int cg      = t & 31;   // cols 4*cg .. 4*cg+3
    const int rs      = t >> 5;   // row slice 0..7; rows rs, rs+8, rs+16, rs+24

    float acc[4][4];
#pragma unroll
    for (int j = 0; j < 4; ++j) {
        float bsum = ba[colbase + 4 * cg + j] + bb[colbase + 4 * cg + j];
#pragma unroll
        for (int i = 0; i < 4; ++i) acc[i][j] = bsum;
    }

    constexpr int KCH = (2 * D) / 128;
    for (int kc = 0; kc < KCH; ++kc) {
        // ---- stage W chunk: sW[j][c] = Wcomb[kc*128+j][colbase+c]
#pragma unroll
        for (int it = 0; it < 16; ++it) {
            int j  = (t >> 5) + it * 8;       // 0..127
            int c4 = (t & 31) * 4;
            int kk = kc * 128 + j;
            const float* src = (kk < D)
                ? (Wa + (size_t)kk * DOUT_T + colbase + c4)
                : (Wb + (size_t)(kk - D) * DOUT_T + colbase + c4);
            *(float4*)&sW[j][c4] = *(const float4*)src;
        }
        // ---- stage input chunk: sIn[r][j] = (kk<D) ? A[row][kk] : A*B
#pragma unroll
        for (int it = 0; it < 4; ++it) {
            int r   = (t >> 5) + it * 8;      // 0..31
            int c4  = (t & 31) * 4;           // 0..124
            int row = rowbase + r;
            int kk  = kc * 128 + c4;
            float4 vin = make_float4(0.f, 0.f, 0.f, 0.f);
            if (row < NN) {
                if (kk < D) {
                    vin = *(const float4*)(A + (size_t)row * D + kk);
                } else {
                    float4 a4 = *(const float4*)(A + (size_t)row * D + kk - D);
                    float4 b4 = *(const float4*)(B + (size_t)row * D + kk - D);
                    vin = make_float4(a4.x * b4.x, a4.y * b4.y,
                                      a4.z * b4.z, a4.w * b4.w);
                }
            }
            *(float4*)&sIn[r][c4] = vin;
        }
        __syncthreads();

        // ---- compute
#pragma unroll 4
        for (int k = 0; k < 128; ++k) {
            float4 w = *(const float4*)&sW[k][cg * 4];
            float a0 = sIn[rs     ][k];
            float a1 = sIn[rs +  8][k];
            float a2 = sIn[rs + 16][k];
            float a3 = sIn[rs + 24][k];
            acc[0][0] += a0 * w.x; acc[0][1] += a0 * w.y; acc[0][2] += a0 * w.z; acc[0][3] += a0 * w.w;
            acc[1][0] += a1 * w.x; acc[1][1] += a1 * w.y; acc[1][2] += a1 * w.z; acc[1][3] += a1 * w.w;
            acc[2][0] += a2 * w.x; acc[2][1] += a2 * w.y; acc[2][2] += a2 * w.z; acc[2][3] += a2 * w.w;
            acc[3][0] += a3 * w.x; acc[3][1] += a3 * w.y; acc[3][2] += a3 * w.z; acc[3][3] += a3 * w.w;
        }
        __syncthreads();
    }

    // ---- epilogue: relu + store
#pragma unroll
    for (int i = 0; i < 4; ++i) {
        int row = rowbase + rs + 8 * i;
        if (row < NN) {
            float4 o;
            o.x = fmaxf(acc[i][0], 0.f);
            o.y = fmaxf(acc[i][1], 0.f);
            o.z = fmaxf(acc[i][2], 0.f);
            o.w = fmaxf(acc[i][3], 0.f);
            *(float4*)(out + (size_t)row * DOUT_T + colbase + cg * 4) = o;
        }
    }
}

// ---------------------------------------------------------------------------
extern "C" void kernel_launch(void* const* d_in, const int* in_sizes, int n_in,
                              void* d_out, int out_size, void* d_ws, size_t ws_size,
                              hipStream_t stream)
{
    const float* l_feat = (const float*)d_in[0];
    const float* r_feat = (const float*)d_in[1];
    const int*   rows   = (const int*)  d_in[2];
    const int*   cols   = (const int*)  d_in[3];
    const float* vals   = (const float*)d_in[4];
    const float* W1     = (const float*)d_in[5];
    const float* b1     = (const float*)d_in[6];
    const float* W2     = (const float*)d_in[7];
    const float* b2     = (const float*)d_in[8];
    const float* W3     = (const float*)d_in[9];
    const float* b3     = (const float*)d_in[10];
    const float* W4     = (const float*)d_in[11];
    const float* b4     = (const float*)d_in[12];
    float* out = (float*)d_out;

    float* ws = (float*)d_ws;
    float* lK = ws;                         // [NN][64]
    float* rK = lK + (size_t)NN * 64;       // [NN][64]
    float* K2 = rK + (size_t)NN * 64;       // [NN][256]
    float* y1 = K2 + (size_t)NN * 256;      // [NN][256]
    float* z1 = y1 + (size_t)NN * 256;      // [NN][256]

    // zero the accumulated buffers (lK, rK, K2 are contiguous): NN*384 floats
    {
        int n4 = NN * 384 / 4;
        zero_kernel<<<(n4 + 255) / 256, 256, 0, stream>>>(lK, n4);
    }

    // SpMM D=64 (both directions in one pass)
    spmm64_kernel<<<NNZE / 4, 256, 0, stream>>>(rows, cols, vals, l_feat, r_feat, lK, rK);

    // layer-1 fused dense: y1 = relu([lK, lK.*l_feat]@[W1;W2]+b1+b2), same for z1
    {
        dim3 grid((NN + 31) / 32, 2);
        dense_kernel<64, 256><<<grid, 256, 0, stream>>>(lK, l_feat, W1, W2, b1, b2, y1);
        dense_kernel<64, 256><<<grid, 256, 0, stream>>>(rK, r_feat, W1, W2, b1, b2, z1);
    }

    // SpMM D=256: K2[r] += v * z1[c]
    spmm256_kernel<<<NNZE / 4, 256, 0, stream>>>(rows, cols, vals, z1, K2);

    // layer-2 fused dense: out = relu([K2, K2.*y1]@[W3;W4]+b3+b4)
    {
        dim3 grid((NN + 31) / 32, 1);
        dense_kernel<256, 128><<<grid, 256, 0, stream>>>(K2, y1, W3, W4, b3, b4, out);
    }
}

// Round 2
// 465.672 us; speedup vs baseline: 1.6034x; 1.6034x over previous
//
#include <hip/hip_runtime.h>

#define NN   30000
#define NNZE 480000

// ---------------------------------------------------------------------------
// zero a float4-aligned region
// ---------------------------------------------------------------------------
__global__ __launch_bounds__(256) void zero_kernel(float* __restrict__ p, int n4) {
    int i = blockIdx.x * blockDim.x + threadIdx.x;
    if (i < n4) ((float4*)p)[i] = make_float4(0.f, 0.f, 0.f, 0.f);
}

// ---------------------------------------------------------------------------
// histogram of row / col indices
// ---------------------------------------------------------------------------
__global__ __launch_bounds__(256) void hist_kernel(
    const int* __restrict__ rows, const int* __restrict__ cols,
    int* __restrict__ rc, int* __restrict__ cc)
{
    int e = blockIdx.x * 256 + threadIdx.x;
    if (e < NNZE) {
        atomicAdd(&rc[rows[e]], 1);
        atomicAdd(&cc[cols[e]], 1);
    }
}

// ---------------------------------------------------------------------------
// exclusive scan of the two 30000-entry histograms (block 0: rows, 1: cols)
// writes ptr[] and a scatter-fill copy fill[]
// ---------------------------------------------------------------------------
__global__ __launch_bounds__(256) void scan2_kernel(
    const int* __restrict__ rc, const int* __restrict__ cc,
    int* __restrict__ rp, int* __restrict__ rf,
    int* __restrict__ cp, int* __restrict__ cf)
{
    const int* cnt = blockIdx.x ? cc : rc;
    int* ptr  = blockIdx.x ? cp : rp;
    int* fill = blockIdx.x ? cf : rf;

    __shared__ int ssum[256];
    const int CH = (NN + 255) / 256;          // 118
    int t = threadIdx.x;
    int base = t * CH;

    int s = 0;
    for (int i = 0; i < CH; ++i) {
        int idx = base + i;
        if (idx < NN) s += cnt[idx];
    }
    ssum[t] = s;
    __syncthreads();
    for (int off = 1; off < 256; off <<= 1) {
        int v = (t >= off) ? ssum[t - off] : 0;
        __syncthreads();
        ssum[t] += v;
        __syncthreads();
    }
    int run = (t == 0) ? 0 : ssum[t - 1];
    for (int i = 0; i < CH; ++i) {
        int idx = base + i;
        if (idx < NN) {
            ptr[idx] = run;
            fill[idx] = run;
            run += cnt[idx];
        }
    }
    if (t == 255) ptr[NN] = NNZE;
}

// ---------------------------------------------------------------------------
// scatter edges into CSR (by row) and CSC (by col) order
// ---------------------------------------------------------------------------
__global__ __launch_bounds__(256) void scatter_kernel(
    const int* __restrict__ rows, const int* __restrict__ cols,
    const float* __restrict__ vals,
    int* __restrict__ rf, int* __restrict__ cf,
    int* __restrict__ csr_col, float* __restrict__ csr_val,
    int* __restrict__ csc_row, float* __restrict__ csc_val)
{
    int e = blockIdx.x * 256 + threadIdx.x;
    if (e < NNZE) {
        int r = rows[e], c = cols[e];
        float v = vals[e];
        int p = atomicAdd(&rf[r], 1);
        csr_col[p] = c; csr_val[p] = v;
        int q = atomicAdd(&cf[c], 1);
        csc_row[q] = r; csc_val[q] = v;
    }
}

// ---------------------------------------------------------------------------
// gather-SpMM D=64: one wave per output row, lane = feature
//   out[w] = sum_e val[e] * feat[idx[e]]
// ---------------------------------------------------------------------------
__global__ __launch_bounds__(256) void gather64_kernel(
    const int* __restrict__ ptr, const int* __restrict__ idx,
    const float* __restrict__ val,
    const float* __restrict__ feat, float* __restrict__ out)
{
    int w    = blockIdx.x * 4 + (threadIdx.x >> 6);
    int lane = threadIdx.x & 63;
    if (w >= NN) return;
    int e0 = ptr[w], e1 = ptr[w + 1];
    float acc = 0.f;
    int e = e0;
    for (; e + 1 < e1; e += 2) {
        int   c0 = idx[e],  c1 = idx[e + 1];
        float v0 = val[e],  v1 = val[e + 1];
        acc += v0 * feat[(size_t)c0 * 64 + lane];
        acc += v1 * feat[(size_t)c1 * 64 + lane];
    }
    if (e < e1) acc += val[e] * feat[(size_t)idx[e] * 64 + lane];
    out[(size_t)w * 64 + lane] = acc;
}

// ---------------------------------------------------------------------------
// gather-SpMM D=256: one 256-thread block per output row
// ---------------------------------------------------------------------------
__global__ __launch_bounds__(256) void gather256_kernel(
    const int* __restrict__ ptr, const int* __restrict__ idx,
    const float* __restrict__ val,
    const float* __restrict__ src, float* __restrict__ out)
{
    int r = blockIdx.x;
    int f = threadIdx.x;
    int e0 = ptr[r], e1 = ptr[r + 1];
    float acc = 0.f;
    int e = e0;
    for (; e + 1 < e1; e += 2) {
        int   c0 = idx[e],  c1 = idx[e + 1];
        float v0 = val[e],  v1 = val[e + 1];
        acc += v0 * src[(size_t)c0 * 256 + f];
        acc += v1 * src[(size_t)c1 * 256 + f];
    }
    if (e < e1) acc += val[e] * src[(size_t)idx[e] * 256 + f];
    out[(size_t)r * 256 + f] = acc;
}

// ---------------------------------------------------------------------------
// Fused dense: out = relu([A, A.*B] @ [Wa; Wb] + ba + bb)   (unchanged)
// ---------------------------------------------------------------------------
template<int D, int DOUT_T>
__global__ __launch_bounds__(256) void dense_kernel(
    const float* __restrict__ A,  const float* __restrict__ B,
    const float* __restrict__ Wa, const float* __restrict__ Wb,
    const float* __restrict__ ba, const float* __restrict__ bb,
    float* __restrict__ out)
{
    __shared__ float sW[128][128];
    __shared__ float sIn[32][128];

    const int t       = threadIdx.x;
    const int rowbase = blockIdx.x * 32;
    const int colbase = blockIdx.y * 128;
    const int cg      = t & 31;
    const int rs      = t >> 5;

    float acc[4][4];
#pragma unroll
    for (int j = 0; j < 4; ++j) {
        float bsum = ba[colbase + 4 * cg + j] + bb[colbase + 4 * cg + j];
#pragma unroll
        for (int i = 0; i < 4; ++i) acc[i][j] = bsum;
    }

    constexpr int KCH = (2 * D) / 128;
    for (int kc = 0; kc < KCH; ++kc) {
#pragma unroll
        for (int it = 0; it < 16; ++it) {
            int j  = (t >> 5) + it * 8;
            int c4 = (t & 31) * 4;
            int kk = kc * 128 + j;
            const float* src = (kk < D)
                ? (Wa + (size_t)kk * DOUT_T + colbase + c4)
                : (Wb + (size_t)(kk - D) * DOUT_T + colbase + c4);
            *(float4*)&sW[j][c4] = *(const float4*)src;
        }
#pragma unroll
        for (int it = 0; it < 4; ++it) {
            int r   = (t >> 5) + it * 8;
            int c4  = (t & 31) * 4;
            int row = rowbase + r;
            int kk  = kc * 128 + c4;
            float4 vin = make_float4(0.f, 0.f, 0.f, 0.f);
            if (row < NN) {
                if (kk < D) {
                    vin = *(const float4*)(A + (size_t)row * D + kk);
                } else {
                    float4 a4 = *(const float4*)(A + (size_t)row * D + kk - D);
                    float4 b4 = *(const float4*)(B + (size_t)row * D + kk - D);
                    vin = make_float4(a4.x * b4.x, a4.y * b4.y,
                                      a4.z * b4.z, a4.w * b4.w);
                }
            }
            *(float4*)&sIn[r][c4] = vin;
        }
        __syncthreads();

#pragma unroll 4
        for (int k = 0; k < 128; ++k) {
            float4 w = *(const float4*)&sW[k][cg * 4];
            float a0 = sIn[rs     ][k];
            float a1 = sIn[rs +  8][k];
            float a2 = sIn[rs + 16][k];
            float a3 = sIn[rs + 24][k];
            acc[0][0] += a0 * w.x; acc[0][1] += a0 * w.y; acc[0][2] += a0 * w.z; acc[0][3] += a0 * w.w;
            acc[1][0] += a1 * w.x; acc[1][1] += a1 * w.y; acc[1][2] += a1 * w.z; acc[1][3] += a1 * w.w;
            acc[2][0] += a2 * w.x; acc[2][1] += a2 * w.y; acc[2][2] += a2 * w.z; acc[2][3] += a2 * w.w;
            acc[3][0] += a3 * w.x; acc[3][1] += a3 * w.y; acc[3][2] += a3 * w.z; acc[3][3] += a3 * w.w;
        }
        __syncthreads();
    }

#pragma unroll
    for (int i = 0; i < 4; ++i) {
        int row = rowbase + rs + 8 * i;
        if (row < NN) {
            float4 o;
            o.x = fmaxf(acc[i][0], 0.f);
            o.y = fmaxf(acc[i][1], 0.f);
            o.z = fmaxf(acc[i][2], 0.f);
            o.w = fmaxf(acc[i][3], 0.f);
            *(float4*)(out + (size_t)row * DOUT_T + colbase + cg * 4) = o;
        }
    }
}

// ---------------------------------------------------------------------------
extern "C" void kernel_launch(void* const* d_in, const int* in_sizes, int n_in,
                              void* d_out, int out_size, void* d_ws, size_t ws_size,
                              hipStream_t stream)
{
    const float* l_feat = (const float*)d_in[0];
    const float* r_feat = (const float*)d_in[1];
    const int*   rows   = (const int*)  d_in[2];
    const int*   cols   = (const int*)  d_in[3];
    const float* vals   = (const float*)d_in[4];
    const float* W1     = (const float*)d_in[5];
    const float* b1     = (const float*)d_in[6];
    const float* W2     = (const float*)d_in[7];
    const float* b2     = (const float*)d_in[8];
    const float* W3     = (const float*)d_in[9];
    const float* b3     = (const float*)d_in[10];
    const float* W4     = (const float*)d_in[11];
    const float* b4     = (const float*)d_in[12];
    float* out = (float*)d_out;

    // ---- workspace layout ----
    float* ws = (float*)d_ws;
    float* lK = ws;                           // [NN][64]
    float* rK = lK + (size_t)NN * 64;         // [NN][64]
    float* K2 = rK + (size_t)NN * 64;         // [NN][256]
    float* y1 = K2 + (size_t)NN * 256;        // [NN][256]
    float* z1 = y1 + (size_t)NN * 256;        // [NN][256]

    // persistent CSR (live until gather256)
    int*   row_ptr = (int*)(z1 + (size_t)NN * 256);   // NN+1
    int*   csr_col = row_ptr + (NN + 1);              // NNZE
    float* csr_val = (float*)(csr_col + NNZE);        // NNZE

    // transient build scratch + CSC — aliased into y1 region (dead before
    // the layer-1 dense writes y1)
    int*   row_cnt  = (int*)y1;                       // NN
    int*   col_cnt  = row_cnt + NN;                   // NN
    int*   row_fill = col_cnt + NN;                   // NN
    int*   col_fill = row_fill + NN;                  // NN
    int*   col_ptr  = col_fill + NN;                  // NN+1
    int*   csc_row  = col_ptr + (NN + 1);             // NNZE
    float* csc_val  = (float*)(csc_row + NNZE);       // NNZE

    // 1. zero the two histograms (2*NN ints, contiguous)
    zero_kernel<<<(2 * NN / 4 + 255) / 256, 256, 0, stream>>>((float*)row_cnt, 2 * NN / 4);

    // 2. histogram
    hist_kernel<<<(NNZE + 255) / 256, 256, 0, stream>>>(rows, cols, row_cnt, col_cnt);

    // 3. scan both histograms
    scan2_kernel<<<2, 256, 0, stream>>>(row_cnt, col_cnt, row_ptr, row_fill, col_ptr, col_fill);

    // 4. scatter into CSR + CSC order
    scatter_kernel<<<(NNZE + 255) / 256, 256, 0, stream>>>(
        rows, cols, vals, row_fill, col_fill, csr_col, csr_val, csc_row, csc_val);

    // 5. gather-SpMM D=64: lK[r] = sum v*r_feat[c],  rK[c] = sum v*l_feat[r]
    gather64_kernel<<<(NN + 3) / 4, 256, 0, stream>>>(row_ptr, csr_col, csr_val, r_feat, lK);
    gather64_kernel<<<(NN + 3) / 4, 256, 0, stream>>>(col_ptr, csc_row, csc_val, l_feat, rK);

    // 6. layer-1 fused dense (CSC scratch dead from here on)
    {
        dim3 grid((NN + 31) / 32, 2);
        dense_kernel<64, 256><<<grid, 256, 0, stream>>>(lK, l_feat, W1, W2, b1, b2, y1);
        dense_kernel<64, 256><<<grid, 256, 0, stream>>>(rK, r_feat, W1, W2, b1, b2, z1);
    }

    // 7. gather-SpMM D=256: K2[r] = sum v*z1[c]
    gather256_kernel<<<NN, 256, 0, stream>>>(row_ptr, csr_col, csr_val, z1, K2);

    // 8. layer-2 fused dense
    {
        dim3 grid((NN + 31) / 32, 1);
        dense_kernel<256, 128><<<grid, 256, 0, stream>>>(K2, y1, W3, W4, b3, b4, out);
    }
}

// Round 3
// 288.403 us; speedup vs baseline: 2.5889x; 1.6147x over previous
//
#include <hip/hip_runtime.h>

#define NN   30000
#define NNZE 480000

using s8 = __attribute__((ext_vector_type(8))) short;  // 8 bf16 = 4 VGPRs
using f4 = __attribute__((ext_vector_type(4))) float;

__device__ __forceinline__ unsigned short f2bf(float x) {
    unsigned int u = __float_as_uint(x);
    u += 0x7fff + ((u >> 16) & 1);          // round-to-nearest-even
    return (unsigned short)(u >> 16);
}
__device__ __forceinline__ float bf2f(unsigned short h) {
    return __uint_as_float(((unsigned int)h) << 16);
}

// ---------------------------------------------------------------------------
__global__ __launch_bounds__(256) void zero_kernel(float* __restrict__ p, int n4) {
    int i = blockIdx.x * blockDim.x + threadIdx.x;
    if (i < n4) ((float4*)p)[i] = make_float4(0.f, 0.f, 0.f, 0.f);
}

// ---------------------------------------------------------------------------
__global__ __launch_bounds__(256) void hist_kernel(
    const int* __restrict__ rows, const int* __restrict__ cols,
    int* __restrict__ rc, int* __restrict__ cc)
{
    int e = blockIdx.x * 256 + threadIdx.x;
    if (e < NNZE) {
        atomicAdd(&rc[rows[e]], 1);
        atomicAdd(&cc[cols[e]], 1);
    }
}

// ---------------------------------------------------------------------------
// hierarchical scan, phase 1: per-block (256-wide) exclusive scan + totals
// blocks 0..117 -> rows, 118..235 -> cols
// ---------------------------------------------------------------------------
#define SCB 118
__global__ __launch_bounds__(256) void scan_local_kernel(
    const int* __restrict__ rc, const int* __restrict__ cc,
    int* __restrict__ rf, int* __restrict__ cf, int* __restrict__ totals)
{
    int b = blockIdx.x;
    const int* cnt = (b < SCB) ? rc : cc;
    int*       esc = (b < SCB) ? rf : cf;
    int lb = (b < SCB) ? b : b - SCB;
    int t = threadIdx.x;
    int idx = lb * 256 + t;

    __shared__ int s[256];
    int v = (idx < NN) ? cnt[idx] : 0;
    s[t] = v;
    __syncthreads();
#pragma unroll
    for (int off = 1; off < 256; off <<= 1) {
        int u = (t >= off) ? s[t - off] : 0;
        __syncthreads();
        s[t] += u;
        __syncthreads();
    }
    if (idx < NN) esc[idx] = s[t] - v;       // exclusive
    if (t == 255) totals[b] = s[t];
}

// phase 2: exclusive scan of the 118 block totals (block 0: rows, 1: cols)
__global__ __launch_bounds__(128) void scan_tot_kernel(int* __restrict__ totals)
{
    int base = blockIdx.x * SCB;
    int t = threadIdx.x;
    __shared__ int s[128];
    int v = (t < SCB) ? totals[base + t] : 0;
    s[t] = v;
    __syncthreads();
#pragma unroll
    for (int off = 1; off < 128; off <<= 1) {
        int u = (t >= off) ? s[t - off] : 0;
        __syncthreads();
        s[t] += u;
        __syncthreads();
    }
    if (t < SCB) totals[base + t] = s[t] - v;
}

// phase 3: add block offsets; write ptr[] and fill[]
__global__ __launch_bounds__(256) void scan_add_kernel(
    int* __restrict__ rf, int* __restrict__ cf,
    int* __restrict__ rp, int* __restrict__ cp,
    const int* __restrict__ totals)
{
    int b = blockIdx.x;
    int lb = (b < SCB) ? b : b - SCB;
    int t = threadIdx.x;
    int idx = lb * 256 + t;
    int off = totals[b];
    if (idx < NN) {
        if (b < SCB) { int v = rf[idx] + off; rp[idx] = v; rf[idx] = v; }
        else         { int v = cf[idx] + off; cp[idx] = v; cf[idx] = v; }
    }
    if (b == 0   && t == 0) rp[NN] = NNZE;
    if (b == SCB && t == 0) cp[NN] = NNZE;
}

// ---------------------------------------------------------------------------
__global__ __launch_bounds__(256) void scatter_kernel(
    const int* __restrict__ rows, const int* __restrict__ cols,
    const float* __restrict__ vals,
    int* __restrict__ rf, int* __restrict__ cf,
    int* __restrict__ csr_col, float* __restrict__ csr_val,
    int* __restrict__ csc_row, float* __restrict__ csc_val)
{
    int e = blockIdx.x * 256 + threadIdx.x;
    if (e < NNZE) {
        int r = rows[e], c = cols[e];
        float v = vals[e];
        int p = atomicAdd(&rf[r], 1);
        csr_col[p] = c; csr_val[p] = v;
        int q = atomicAdd(&cf[c], 1);
        csc_row[q] = r; csc_val[q] = v;
    }
}

// ---------------------------------------------------------------------------
// gather-SpMM D=64 fused with GEMM-input prep:
//   acc = sum_e val*gfeat[idx[e]];  X[w] = [bf16(acc), bf16(acc*mfeat[w])]
// ---------------------------------------------------------------------------
__global__ __launch_bounds__(256) void gather64_x_kernel(
    const int* __restrict__ ptr, const int* __restrict__ idx,
    const float* __restrict__ val,
    const float* __restrict__ gfeat, const float* __restrict__ mfeat,
    unsigned short* __restrict__ X)
{
    int w    = blockIdx.x * 4 + (threadIdx.x >> 6);
    int lane = threadIdx.x & 63;
    if (w >= NN) return;
    int e0 = ptr[w], e1 = ptr[w + 1];
    float acc = 0.f;
    int e = e0;
    for (; e + 1 < e1; e += 2) {
        int   c0 = idx[e],  c1 = idx[e + 1];
        float v0 = val[e],  v1 = val[e + 1];
        acc += v0 * gfeat[(size_t)c0 * 64 + lane];
        acc += v1 * gfeat[(size_t)c1 * 64 + lane];
    }
    if (e < e1) acc += val[e] * gfeat[(size_t)idx[e] * 64 + lane];
    float m = acc * mfeat[(size_t)w * 64 + lane];
    X[(size_t)w * 128 + lane]      = f2bf(acc);
    X[(size_t)w * 128 + 64 + lane] = f2bf(m);
}

// ---------------------------------------------------------------------------
// gather-SpMM D=256 fused with layer-2 GEMM-input prep:
//   acc = sum_e val*z1[idx[e]];  X3[r] = [bf16(acc), bf16(acc*y1[r])]
// ---------------------------------------------------------------------------
__global__ __launch_bounds__(256) void gather256_x_kernel(
    const int* __restrict__ ptr, const int* __restrict__ idx,
    const float* __restrict__ val,
    const float* __restrict__ z1, const unsigned short* __restrict__ y1b,
    unsigned short* __restrict__ X3)
{
    int r = blockIdx.x;
    int f = threadIdx.x;
    int e0 = ptr[r], e1 = ptr[r + 1];
    float acc = 0.f;
    int e = e0;
    for (; e + 1 < e1; e += 2) {
        int   c0 = idx[e],  c1 = idx[e + 1];
        float v0 = val[e],  v1 = val[e + 1];
        acc += v0 * z1[(size_t)c0 * 256 + f];
        acc += v1 * z1[(size_t)c1 * 256 + f];
    }
    if (e < e1) acc += val[e] * z1[(size_t)idx[e] * 256 + f];
    float y = bf2f(y1b[(size_t)r * 256 + f]);
    X3[(size_t)r * 512 + f]       = f2bf(acc);
    X3[(size_t)r * 512 + 256 + f] = f2bf(acc * y);
}

// ---------------------------------------------------------------------------
// weight prep: Wt1[n][k] = bf16(Wc1[k][n]) (n<256,k<128),
//              Wt2[n][k] = bf16(Wc2[k][n]) (n<128,k<512), bias sums
// ---------------------------------------------------------------------------
__global__ __launch_bounds__(256) void wprep_kernel(
    const float* __restrict__ W1, const float* __restrict__ W2,
    const float* __restrict__ W3, const float* __restrict__ W4,
    const float* __restrict__ b1, const float* __restrict__ b2,
    const float* __restrict__ b3, const float* __restrict__ b4,
    unsigned short* __restrict__ Wt1, unsigned short* __restrict__ Wt2,
    float* __restrict__ bias1, float* __restrict__ bias2)
{
    int i = blockIdx.x * 256 + threadIdx.x;
    if (i < 32768) {                       // Wt1: [256][128]
        int n = i >> 7, k = i & 127;
        float v = (k < 64) ? W1[(size_t)k * 256 + n] : W2[(size_t)(k - 64) * 256 + n];
        Wt1[i] = f2bf(v);
    } else if (i < 32768 + 65536) {        // Wt2: [128][512]
        int j = i - 32768;
        int n = j >> 9, k = j & 511;
        float v = (k < 256) ? W3[(size_t)k * 128 + n] : W4[(size_t)(k - 256) * 128 + n];
        Wt2[j] = f2bf(v);
    } else if (i < 98304 + 256) {
        int n = i - 98304; bias1[n] = b1[n] + b2[n];
    } else if (i < 98560 + 128) {
        int n = i - 98560; bias2[n] = b3[n] + b4[n];
    }
}

// ---------------------------------------------------------------------------
// MFMA GEMM: out = relu(X[NN][K] @ Wt^T + bias), Wt stored [DOUT][K] bf16.
// Block: 256 thr = 4 waves (2x2), tile 64x64, K chunks of 64.
// LDS 16KB, XOR-swizzled 16B chunks to kill the stride-128B bank conflict.
// ---------------------------------------------------------------------------
template<int K, int DOUT, bool OUT_BF16>
__global__ __launch_bounds__(256) void mfma_gemm_kernel(
    const unsigned short* __restrict__ X, const unsigned short* __restrict__ Wt,
    const float* __restrict__ bias, void* __restrict__ outv)
{
    __shared__ s8 sX[64 * 8];   // [row][chunk] 16B chunks, chunk ^= row&7
    __shared__ s8 sW[64 * 8];

    const int t       = threadIdx.x;
    const int rowbase = blockIdx.x * 64;
    const int colbase = blockIdx.y * 64;
    const int wid     = t >> 6;
    const int lane    = t & 63;
    const int wm      = wid >> 1;   // 0..1
    const int wn      = wid & 1;    // 0..1
    const int l15     = lane & 15;
    const int kg      = lane >> 4;  // 0..3

    f4 acc[2][2] = {};

    for (int kc = 0; kc < K; kc += 64) {
        // stage X tile (64 rows x 64 bf16) and W tile
#pragma unroll
        for (int it = 0; it < 2; ++it) {
            int r = (t >> 3) + it * 32;
            int c = t & 7;
            int row = rowbase + r;
            s8 v = {};
            if (row < NN)
                v = ((const s8*)X)[((size_t)row * K + kc) / 8 + c];
            sX[r * 8 + (c ^ (r & 7))] = v;
            int n = colbase + r;
            sW[r * 8 + (c ^ (r & 7))] = ((const s8*)Wt)[((size_t)n * K + kc) / 8 + c];
        }
        __syncthreads();

#pragma unroll
        for (int ks = 0; ks < 2; ++ks) {
            int cch = ks * 4 + kg;
            s8 a[2], b[2];
#pragma unroll
            for (int fm = 0; fm < 2; ++fm) {
                int r0 = wm * 32 + fm * 16 + l15;
                a[fm] = sX[r0 * 8 + (cch ^ (r0 & 7))];
            }
#pragma unroll
            for (int fn = 0; fn < 2; ++fn) {
                int n0 = wn * 32 + fn * 16 + l15;
                b[fn] = sW[n0 * 8 + (cch ^ (n0 & 7))];
            }
#pragma unroll
            for (int fm = 0; fm < 2; ++fm)
#pragma unroll
                for (int fn = 0; fn < 2; ++fn)
                    acc[fm][fn] = __builtin_amdgcn_mfma_f32_16x16x32_bf16(
                        a[fm], b[fn], acc[fm][fn], 0, 0, 0);
        }
        __syncthreads();
    }

    // epilogue: C/D layout col=lane&15, row=(lane>>4)*4+j
#pragma unroll
    for (int fm = 0; fm < 2; ++fm) {
#pragma unroll
        for (int fn = 0; fn < 2; ++fn) {
            int col = colbase + wn * 32 + fn * 16 + l15;
            float bv = bias[col];
#pragma unroll
            for (int j = 0; j < 4; ++j) {
                int row = rowbase + wm * 32 + fm * 16 + kg * 4 + j;
                if (row < NN) {
                    float v = fmaxf(acc[fm][fn][j] + bv, 0.f);
                    if (OUT_BF16)
                        ((unsigned short*)outv)[(size_t)row * DOUT + col] = f2bf(v);
                    else
                        ((float*)outv)[(size_t)row * DOUT + col] = v;
                }
            }
        }
    }
}

// ---------------------------------------------------------------------------
extern "C" void kernel_launch(void* const* d_in, const int* in_sizes, int n_in,
                              void* d_out, int out_size, void* d_ws, size_t ws_size,
                              hipStream_t stream)
{
    const float* l_feat = (const float*)d_in[0];
    const float* r_feat = (const float*)d_in[1];
    const int*   rows   = (const int*)  d_in[2];
    const int*   cols   = (const int*)  d_in[3];
    const float* vals   = (const float*)d_in[4];
    const float* W1     = (const float*)d_in[5];
    const float* b1     = (const float*)d_in[6];
    const float* W2     = (const float*)d_in[7];
    const float* b2     = (const float*)d_in[8];
    const float* W3     = (const float*)d_in[9];
    const float* b3     = (const float*)d_in[10];
    const float* W4     = (const float*)d_in[11];
    const float* b4     = (const float*)d_in[12];
    float* out = (float*)d_out;

    // ---- workspace carve (all 16B-aligned region starts) ----
    char* p = (char*)d_ws;
    unsigned short* X1  = (unsigned short*)p; p += (size_t)NN * 128 * 2;  // bf16 [NN][128]
    unsigned short* X2  = (unsigned short*)p; p += (size_t)NN * 128 * 2;
    unsigned short* X3  = (unsigned short*)p; p += (size_t)NN * 512 * 2;  // bf16 [NN][512]
    float*          z1  = (float*)p;          p += (size_t)NN * 256 * 4;  // f32 [NN][256]
    unsigned short* y1b = (unsigned short*)p; p += (size_t)NN * 256 * 2;  // bf16 [NN][256]
    int* row_cnt  = (int*)p; p += (size_t)NN * 4;
    int* col_cnt  = (int*)p; p += (size_t)NN * 4;
    int* row_fill = (int*)p; p += (size_t)NN * 4;   // also holds local escan
    int* col_fill = (int*)p; p += (size_t)NN * 4;
    int* totals   = (int*)p; p += 256 * 4;          // 236 used
    unsigned short* Wt1 = (unsigned short*)p; p += 32768 * 2;
    unsigned short* Wt2 = (unsigned short*)p; p += 65536 * 2;
    float* bias1 = (float*)p; p += 256 * 4;
    float* bias2 = (float*)p; p += 128 * 4;
    int*   row_ptr = (int*)p; p += (size_t)(NN + 1) * 4;
    int*   col_ptr = (int*)p; p += (size_t)(NN + 1) * 4;
    int*   csr_col = (int*)p; p += (size_t)NNZE * 4;
    float* csr_val = (float*)p; p += (size_t)NNZE * 4;
    int*   csc_row = (int*)p; p += (size_t)NNZE * 4;
    float* csc_val = (float*)p; p += (size_t)NNZE * 4;

    // 1. weight prep (no deps) + zero histograms
    wprep_kernel<<<(98688 + 255) / 256, 256, 0, stream>>>(
        W1, W2, W3, W4, b1, b2, b3, b4, Wt1, Wt2, bias1, bias2);
    zero_kernel<<<(2 * NN / 4 + 255) / 256, 256, 0, stream>>>((float*)row_cnt, 2 * NN / 4);

    // 2. histogram
    hist_kernel<<<(NNZE + 255) / 256, 256, 0, stream>>>(rows, cols, row_cnt, col_cnt);

    // 3. hierarchical scan
    scan_local_kernel<<<2 * SCB, 256, 0, stream>>>(row_cnt, col_cnt, row_fill, col_fill, totals);
    scan_tot_kernel<<<2, 128, 0, stream>>>(totals);
    scan_add_kernel<<<2 * SCB, 256, 0, stream>>>(row_fill, col_fill, row_ptr, col_ptr, totals);

    // 4. scatter into CSR + CSC order
    scatter_kernel<<<(NNZE + 255) / 256, 256, 0, stream>>>(
        rows, cols, vals, row_fill, col_fill, csr_col, csr_val, csc_row, csc_val);

    // 5. gather-SpMM D=64 fused with bf16 GEMM-input prep
    gather64_x_kernel<<<(NN + 3) / 4, 256, 0, stream>>>(row_ptr, csr_col, csr_val, r_feat, l_feat, X1);
    gather64_x_kernel<<<(NN + 3) / 4, 256, 0, stream>>>(col_ptr, csc_row, csc_val, l_feat, r_feat, X2);

    // 6. layer-1 MFMA GEMMs: y1 (bf16, feeds elementwise), z1 (f32, feeds gather)
    {
        dim3 grid((NN + 63) / 64, 256 / 64);
        mfma_gemm_kernel<128, 256, true ><<<grid, 256, 0, stream>>>(X1, Wt1, bias1, y1b);
        mfma_gemm_kernel<128, 256, false><<<grid, 256, 0, stream>>>(X2, Wt1, bias1, z1);
    }

    // 7. gather-SpMM D=256 fused with layer-2 input prep
    gather256_x_kernel<<<NN, 256, 0, stream>>>(row_ptr, csr_col, csr_val, z1, y1b, X3);

    // 8. layer-2 MFMA GEMM -> output
    {
        dim3 grid((NN + 63) / 64, 128 / 64);
        mfma_gemm_kernel<512, 128, false><<<grid, 256, 0, stream>>>(X3, Wt2, bias2, out);
    }
}

// Round 4
// 270.032 us; speedup vs baseline: 2.7650x; 1.0680x over previous
//
#include <hip/hip_runtime.h>

#define NN   30000
#define NNZE 480000

using s8 = __attribute__((ext_vector_type(8))) short;  // 8 bf16 = 4 VGPRs
using f4 = __attribute__((ext_vector_type(4))) float;

__device__ __forceinline__ unsigned short f2bf(float x) {
    unsigned int u = __float_as_uint(x);
    u += 0x7fff + ((u >> 16) & 1);          // round-to-nearest-even
    return (unsigned short)(u >> 16);
}
__device__ __forceinline__ float bf2f(unsigned short h) {
    return __uint_as_float(((unsigned int)h) << 16);
}

// ---------------------------------------------------------------------------
__global__ __launch_bounds__(256) void zero_kernel(float* __restrict__ p, int n4) {
    int i = blockIdx.x * blockDim.x + threadIdx.x;
    if (i < n4) ((float4*)p)[i] = make_float4(0.f, 0.f, 0.f, 0.f);
}

// ---------------------------------------------------------------------------
__global__ __launch_bounds__(256) void hist_kernel(
    const int* __restrict__ rows, const int* __restrict__ cols,
    int* __restrict__ rc, int* __restrict__ cc)
{
    int e = blockIdx.x * 256 + threadIdx.x;
    if (e < NNZE) {
        atomicAdd(&rc[rows[e]], 1);
        atomicAdd(&cc[cols[e]], 1);
    }
}

// ---------------------------------------------------------------------------
// hierarchical scan (3 phases); blocks 0..117 rows, 118..235 cols
// ---------------------------------------------------------------------------
#define SCB 118
__global__ __launch_bounds__(256) void scan_local_kernel(
    const int* __restrict__ rc, const int* __restrict__ cc,
    int* __restrict__ rf, int* __restrict__ cf, int* __restrict__ totals)
{
    int b = blockIdx.x;
    const int* cnt = (b < SCB) ? rc : cc;
    int*       esc = (b < SCB) ? rf : cf;
    int lb = (b < SCB) ? b : b - SCB;
    int t = threadIdx.x;
    int idx = lb * 256 + t;

    __shared__ int s[256];
    int v = (idx < NN) ? cnt[idx] : 0;
    s[t] = v;
    __syncthreads();
#pragma unroll
    for (int off = 1; off < 256; off <<= 1) {
        int u = (t >= off) ? s[t - off] : 0;
        __syncthreads();
        s[t] += u;
        __syncthreads();
    }
    if (idx < NN) esc[idx] = s[t] - v;       // exclusive
    if (t == 255) totals[b] = s[t];
}

__global__ __launch_bounds__(128) void scan_tot_kernel(int* __restrict__ totals)
{
    int base = blockIdx.x * SCB;
    int t = threadIdx.x;
    __shared__ int s[128];
    int v = (t < SCB) ? totals[base + t] : 0;
    s[t] = v;
    __syncthreads();
#pragma unroll
    for (int off = 1; off < 128; off <<= 1) {
        int u = (t >= off) ? s[t - off] : 0;
        __syncthreads();
        s[t] += u;
        __syncthreads();
    }
    if (t < SCB) totals[base + t] = s[t] - v;
}

__global__ __launch_bounds__(256) void scan_add_kernel(
    int* __restrict__ rf, int* __restrict__ cf,
    int* __restrict__ rp, int* __restrict__ cp,
    const int* __restrict__ totals)
{
    int b = blockIdx.x;
    int lb = (b < SCB) ? b : b - SCB;
    int t = threadIdx.x;
    int idx = lb * 256 + t;
    int off = totals[b];
    if (idx < NN) {
        if (b < SCB) { int v = rf[idx] + off; rp[idx] = v; rf[idx] = v; }
        else         { int v = cf[idx] + off; cp[idx] = v; cf[idx] = v; }
    }
    if (b == 0   && t == 0) rp[NN] = NNZE;
    if (b == SCB && t == 0) cp[NN] = NNZE;
}

// ---------------------------------------------------------------------------
// scatter edges into CSR/CSC order; (idx, valbits) packed as int2
// ---------------------------------------------------------------------------
__global__ __launch_bounds__(256) void scatter_kernel(
    const int* __restrict__ rows, const int* __restrict__ cols,
    const float* __restrict__ vals,
    int* __restrict__ rf, int* __restrict__ cf,
    int2* __restrict__ csr_pair, int2* __restrict__ csc_pair)
{
    int e = blockIdx.x * 256 + threadIdx.x;
    if (e < NNZE) {
        int r = rows[e], c = cols[e];
        int vb = __float_as_int(vals[e]);
        int p = atomicAdd(&rf[r], 1);
        csr_pair[p] = make_int2(c, vb);
        int q = atomicAdd(&cf[c], 1);
        csc_pair[q] = make_int2(r, vb);
    }
}

// ---------------------------------------------------------------------------
// convert l_feat / r_feat to bf16
// ---------------------------------------------------------------------------
__global__ __launch_bounds__(256) void featb_kernel(
    const float* __restrict__ a, const float* __restrict__ b,
    unsigned short* __restrict__ ab, unsigned short* __restrict__ bb)
{
    const int n4 = NN * 64 / 4;   // 480000
    int i = blockIdx.x * 256 + threadIdx.x;
    const float* src = (i < n4) ? a : b;
    unsigned short* dst = (i < n4) ? ab : bb;
    int j = (i < n4) ? i : i - n4;
    if (i < 2 * n4) {
        float4 v = ((const float4*)src)[j];
        ushort4 o;
        o.x = f2bf(v.x); o.y = f2bf(v.y); o.z = f2bf(v.z); o.w = f2bf(v.w);
        ((ushort4*)dst)[j] = o;
    }
}

// ---------------------------------------------------------------------------
// gather-SpMM D=64 (both directions via blockIdx.y), bf16 feats:
//   acc = sum v*gf[idx]; X = [bf16(acc), bf16(acc*mf[w])]
// ---------------------------------------------------------------------------
__global__ __launch_bounds__(256) void gather64_x_kernel(
    const int* __restrict__ rp, const int2* __restrict__ rpair,
    const int* __restrict__ cp, const int2* __restrict__ cpair,
    const unsigned short* __restrict__ lfb, const unsigned short* __restrict__ rfb,
    unsigned short* __restrict__ X1, unsigned short* __restrict__ X2)
{
    int side = blockIdx.y;
    const int*  ptr  = side ? cp    : rp;
    const int2* pair = side ? cpair : rpair;
    const unsigned short* gf = side ? lfb : rfb;
    const unsigned short* mf = side ? rfb : lfb;
    unsigned short* X = side ? X2 : X1;

    int w    = blockIdx.x * 4 + (threadIdx.x >> 6);
    int lane = threadIdx.x & 63;
    int e0 = ptr[w], e1 = ptr[w + 1];
    float acc = 0.f;
    int e = e0;
    for (; e + 1 < e1; e += 2) {
        int2 p0 = pair[e], p1 = pair[e + 1];
        acc += __int_as_float(p0.y) * bf2f(gf[(size_t)p0.x * 64 + lane]);
        acc += __int_as_float(p1.y) * bf2f(gf[(size_t)p1.x * 64 + lane]);
    }
    if (e < e1) {
        int2 p0 = pair[e];
        acc += __int_as_float(p0.y) * bf2f(gf[(size_t)p0.x * 64 + lane]);
    }
    float m = acc * bf2f(mf[(size_t)w * 64 + lane]);
    X[(size_t)w * 128 + lane]      = f2bf(acc);
    X[(size_t)w * 128 + 64 + lane] = f2bf(m);
}

// ---------------------------------------------------------------------------
// gather-SpMM D=256, wave-per-row, bf16 z1:
//   acc[0..3] = sum v*z1b[idx]; X3 = [bf16(acc), bf16(acc*y1b[r])]
// ---------------------------------------------------------------------------
__global__ __launch_bounds__(256) void gather256_x_kernel(
    const int* __restrict__ ptr, const int2* __restrict__ pair,
    const unsigned short* __restrict__ z1b, const unsigned short* __restrict__ y1b,
    unsigned short* __restrict__ X3)
{
    int w    = blockIdx.x * 4 + (threadIdx.x >> 6);
    int lane = threadIdx.x & 63;
    int e0 = ptr[w], e1 = ptr[w + 1];
    const ushort4* Z = (const ushort4*)z1b;   // row stride 64 ushort4
    f4 acc = {0.f, 0.f, 0.f, 0.f};
    int e = e0;
    for (; e + 1 < e1; e += 2) {
        int2 p0 = pair[e], p1 = pair[e + 1];
        float v0 = __int_as_float(p0.y), v1 = __int_as_float(p1.y);
        ushort4 z0 = Z[(size_t)p0.x * 64 + lane];
        ushort4 z1 = Z[(size_t)p1.x * 64 + lane];
        acc[0] += v0 * bf2f(z0.x) + v1 * bf2f(z1.x);
        acc[1] += v0 * bf2f(z0.y) + v1 * bf2f(z1.y);
        acc[2] += v0 * bf2f(z0.z) + v1 * bf2f(z1.z);
        acc[3] += v0 * bf2f(z0.w) + v1 * bf2f(z1.w);
    }
    if (e < e1) {
        int2 p0 = pair[e];
        float v0 = __int_as_float(p0.y);
        ushort4 z0 = Z[(size_t)p0.x * 64 + lane];
        acc[0] += v0 * bf2f(z0.x);
        acc[1] += v0 * bf2f(z0.y);
        acc[2] += v0 * bf2f(z0.z);
        acc[3] += v0 * bf2f(z0.w);
    }
    ushort4 y = ((const ushort4*)y1b)[(size_t)w * 64 + lane];
    ushort4 o0, o1;
    o0.x = f2bf(acc[0]); o0.y = f2bf(acc[1]); o0.z = f2bf(acc[2]); o0.w = f2bf(acc[3]);
    o1.x = f2bf(acc[0] * bf2f(y.x));
    o1.y = f2bf(acc[1] * bf2f(y.y));
    o1.z = f2bf(acc[2] * bf2f(y.z));
    o1.w = f2bf(acc[3] * bf2f(y.w));
    ((ushort4*)X3)[(size_t)w * 128 + lane]      = o0;
    ((ushort4*)X3)[(size_t)w * 128 + 64 + lane] = o1;
}

// ---------------------------------------------------------------------------
// weight prep (transpose to [DOUT][K] bf16) + bias sums
// ---------------------------------------------------------------------------
__global__ __launch_bounds__(256) void wprep_kernel(
    const float* __restrict__ W1, const float* __restrict__ W2,
    const float* __restrict__ W3, const float* __restrict__ W4,
    const float* __restrict__ b1, const float* __restrict__ b2,
    const float* __restrict__ b3, const float* __restrict__ b4,
    unsigned short* __restrict__ Wt1, unsigned short* __restrict__ Wt2,
    float* __restrict__ bias1, float* __restrict__ bias2)
{
    int i = blockIdx.x * 256 + threadIdx.x;
    if (i < 32768) {                       // Wt1: [256][128]
        int n = i >> 7, k = i & 127;
        float v = (k < 64) ? W1[(size_t)k * 256 + n] : W2[(size_t)(k - 64) * 256 + n];
        Wt1[i] = f2bf(v);
    } else if (i < 32768 + 65536) {        // Wt2: [128][512]
        int j = i - 32768;
        int n = j >> 9, k = j & 511;
        float v = (k < 256) ? W3[(size_t)k * 128 + n] : W4[(size_t)(k - 256) * 128 + n];
        Wt2[j] = f2bf(v);
    } else if (i < 98304 + 256) {
        int n = i - 98304; bias1[n] = b1[n] + b2[n];
    } else if (i < 98560 + 128) {
        int n = i - 98560; bias2[n] = b3[n] + b4[n];
    }
}

// ---------------------------------------------------------------------------
// MFMA GEMM: out = relu(X[NN][K] @ Wt^T + bias), Wt [DOUT][K] bf16.
// Block: 4 waves, tile 64 rows x DOUT cols (wave owns 64 x DOUT/4).
// K chunks of 64; LDS XOR-swizzled 16B chunks (bank-conflict-free).
// X is read exactly once from HBM; W tiles are L2-resident.
// ---------------------------------------------------------------------------
template<int K, int DOUT, bool OUT_BF16>
__global__ __launch_bounds__(256) void mfma_gemm_kernel(
    const unsigned short* __restrict__ X, const unsigned short* __restrict__ Wt,
    const float* __restrict__ bias, void* __restrict__ outv)
{
    constexpr int WC = DOUT / 4;       // cols per wave (64 or 32)
    constexpr int FN = WC / 16;        // 4 or 2
    __shared__ s8 sX[64 * 8];          // [row][chunk], chunk ^= row&7
    __shared__ s8 sW[DOUT * 8];

    const int t       = threadIdx.x;
    const int rowbase = blockIdx.x * 64;
    const int wid     = t >> 6;
    const int lane    = t & 63;
    const int l15     = lane & 15;
    const int kg      = lane >> 4;

    f4 acc[4][FN] = {};

    for (int kc = 0; kc < K; kc += 64) {
        // stage X tile: 512 chunks, 2 per thread
#pragma unroll
        for (int it = 0; it < 2; ++it) {
            int ch = t + it * 256;
            int r = ch >> 3, c = ch & 7;
            int row = rowbase + r;
            s8 v = {};
            if (row < NN) v = ((const s8*)X)[((size_t)row * K + kc) / 8 + c];
            sX[(r << 3) | (c ^ (r & 7))] = v;
        }
        // stage W tile: DOUT*8 chunks
#pragma unroll
        for (int it = 0; it < DOUT / 32; ++it) {
            int ch = t + it * 256;
            int n = ch >> 3, c = ch & 7;
            sW[(n << 3) | (c ^ (n & 7))] = ((const s8*)Wt)[((size_t)n * K + kc) / 8 + c];
        }
        __syncthreads();

#pragma unroll
        for (int ks = 0; ks < 2; ++ks) {
            int cch = ks * 4 + kg;
            s8 a[4], b[FN];
#pragma unroll
            for (int fm = 0; fm < 4; ++fm) {
                int r0 = fm * 16 + l15;
                a[fm] = sX[(r0 << 3) | (cch ^ (r0 & 7))];
            }
#pragma unroll
            for (int fn = 0; fn < FN; ++fn) {
                int n0 = wid * WC + fn * 16 + l15;
                b[fn] = sW[(n0 << 3) | (cch ^ (n0 & 7))];
            }
#pragma unroll
            for (int fm = 0; fm < 4; ++fm)
#pragma unroll
                for (int fn = 0; fn < FN; ++fn)
                    acc[fm][fn] = __builtin_amdgcn_mfma_f32_16x16x32_bf16(
                        a[fm], b[fn], acc[fm][fn], 0, 0, 0);
        }
        __syncthreads();
    }

    // epilogue: C/D layout col=lane&15, row=kg*4+j
#pragma unroll
    for (int fm = 0; fm < 4; ++fm) {
#pragma unroll
        for (int fn = 0; fn < FN; ++fn) {
            int col = wid * WC + fn * 16 + l15;
            float bv = bias[col];
#pragma unroll
            for (int j = 0; j < 4; ++j) {
                int row = rowbase + fm * 16 + kg * 4 + j;
                if (row < NN) {
                    float v = fmaxf(acc[fm][fn][j] + bv, 0.f);
                    if constexpr (OUT_BF16)
                        ((unsigned short*)outv)[(size_t)row * DOUT + col] = f2bf(v);
                    else
                        ((float*)outv)[(size_t)row * DOUT + col] = v;
                }
            }
        }
    }
}

// ---------------------------------------------------------------------------
extern "C" void kernel_launch(void* const* d_in, const int* in_sizes, int n_in,
                              void* d_out, int out_size, void* d_ws, size_t ws_size,
                              hipStream_t stream)
{
    const float* l_feat = (const float*)d_in[0];
    const float* r_feat = (const float*)d_in[1];
    const int*   rows   = (const int*)  d_in[2];
    const int*   cols   = (const int*)  d_in[3];
    const float* vals   = (const float*)d_in[4];
    const float* W1     = (const float*)d_in[5];
    const float* b1     = (const float*)d_in[6];
    const float* W2     = (const float*)d_in[7];
    const float* b2     = (const float*)d_in[8];
    const float* W3     = (const float*)d_in[9];
    const float* b3     = (const float*)d_in[10];
    const float* W4     = (const float*)d_in[11];
    const float* b4     = (const float*)d_in[12];
    float* out = (float*)d_out;

    // ---- workspace carve ----
    char* p = (char*)d_ws;
    unsigned short* X1  = (unsigned short*)p; p += (size_t)NN * 128 * 2;
    unsigned short* X2  = (unsigned short*)p; p += (size_t)NN * 128 * 2;
    unsigned short* X3  = (unsigned short*)p; p += (size_t)NN * 512 * 2;
    unsigned short* z1b = (unsigned short*)p; p += (size_t)NN * 256 * 2;
    unsigned short* y1b = (unsigned short*)p; p += (size_t)NN * 256 * 2;
    unsigned short* lfb = (unsigned short*)p; p += (size_t)NN * 64 * 2;
    unsigned short* rfb = (unsigned short*)p; p += (size_t)NN * 64 * 2;
    int* row_cnt  = (int*)p; p += (size_t)NN * 4;
    int* col_cnt  = (int*)p; p += (size_t)NN * 4;
    int* row_fill = (int*)p; p += (size_t)NN * 4;
    int* col_fill = (int*)p; p += (size_t)NN * 4;
    int* totals   = (int*)p; p += 256 * 4;
    unsigned short* Wt1 = (unsigned short*)p; p += 32768 * 2;
    unsigned short* Wt2 = (unsigned short*)p; p += 65536 * 2;
    float* bias1 = (float*)p; p += 256 * 4;
    float* bias2 = (float*)p; p += 128 * 4;
    int*   row_ptr  = (int*)p; p += (size_t)(NN + 4) * 4;
    int*   col_ptr  = (int*)p; p += (size_t)(NN + 4) * 4;
    int2*  csr_pair = (int2*)p; p += (size_t)NNZE * 8;
    int2*  csc_pair = (int2*)p; p += (size_t)NNZE * 8;

    // 1. independent prep: weights, feat conversion, zero histograms
    wprep_kernel<<<(98688 + 255) / 256, 256, 0, stream>>>(
        W1, W2, W3, W4, b1, b2, b3, b4, Wt1, Wt2, bias1, bias2);
    featb_kernel<<<(2 * NN * 64 / 4 + 255) / 256, 256, 0, stream>>>(l_feat, r_feat, lfb, rfb);
    zero_kernel<<<(2 * NN / 4 + 255) / 256, 256, 0, stream>>>((float*)row_cnt, 2 * NN / 4);

    // 2. histogram
    hist_kernel<<<(NNZE + 255) / 256, 256, 0, stream>>>(rows, cols, row_cnt, col_cnt);

    // 3. hierarchical scan
    scan_local_kernel<<<2 * SCB, 256, 0, stream>>>(row_cnt, col_cnt, row_fill, col_fill, totals);
    scan_tot_kernel<<<2, 128, 0, stream>>>(totals);
    scan_add_kernel<<<2 * SCB, 256, 0, stream>>>(row_fill, col_fill, row_ptr, col_ptr, totals);

    // 4. scatter into CSR + CSC order (packed pairs)
    scatter_kernel<<<(NNZE + 255) / 256, 256, 0, stream>>>(
        rows, cols, vals, row_fill, col_fill, csr_pair, csc_pair);

    // 5. gather-SpMM D=64, both directions in one launch
    {
        dim3 grid(NN / 4, 2);
        gather64_x_kernel<<<grid, 256, 0, stream>>>(
            row_ptr, csr_pair, col_ptr, csc_pair, lfb, rfb, X1, X2);
    }

    // 6. layer-1 MFMA GEMMs (both bf16 out)
    {
        dim3 grid((NN + 63) / 64);
        mfma_gemm_kernel<128, 256, true><<<grid, 256, 0, stream>>>(X1, Wt1, bias1, y1b);
        mfma_gemm_kernel<128, 256, true><<<grid, 256, 0, stream>>>(X2, Wt1, bias1, z1b);
    }

    // 7. gather-SpMM D=256 (bf16 z1), fused layer-2 input prep
    gather256_x_kernel<<<NN / 4, 256, 0, stream>>>(row_ptr, csr_pair, z1b, y1b, X3);

    // 8. layer-2 MFMA GEMM -> output (f32)
    {
        dim3 grid((NN + 63) / 64);
        mfma_gemm_kernel<512, 128, false><<<grid, 256, 0, stream>>>(X3, Wt2, bias2, out);
    }
}

// Round 5
// 222.126 us; speedup vs baseline: 3.3614x; 1.2157x over previous
//
#include <hip/hip_runtime.h>

#define NN    30000
#define NNZE  480000
#define NPART 8
#define PROWS (NN / NPART)     // 3750, exact

using s8 = __attribute__((ext_vector_type(8))) short;  // 8 bf16 = 4 VGPRs
using f4 = __attribute__((ext_vector_type(4))) float;

__device__ __forceinline__ unsigned short f2bf(float x) {
    unsigned int u = __float_as_uint(x);
    u += 0x7fff + ((u >> 16) & 1);          // round-to-nearest-even
    return (unsigned short)(u >> 16);
}
__device__ __forceinline__ float bf2f(unsigned short h) {
    return __uint_as_float(((unsigned int)h) << 16);
}

// ---------------------------------------------------------------------------
// fused prep: feat->bf16 conversion, weight transpose->bf16, bias sums,
// and zeroing of the 2*NN histogram counters
// ---------------------------------------------------------------------------
#define FEAT4   (NN * 64 / 4)              // 480000 float4 groups per feat
#define PREP_W0 (2 * FEAT4)                // 960000
#define PREP_W1 (PREP_W0 + 98688)          // wprep range
#define PREP_Z  (PREP_W1 + 2 * NN / 4)     // zero range (int4)
__global__ __launch_bounds__(256) void prep_kernel(
    const float* __restrict__ lf, const float* __restrict__ rf,
    const float* __restrict__ W1, const float* __restrict__ W2,
    const float* __restrict__ W3, const float* __restrict__ W4,
    const float* __restrict__ b1, const float* __restrict__ b2,
    const float* __restrict__ b3, const float* __restrict__ b4,
    unsigned short* __restrict__ lfb, unsigned short* __restrict__ rfb,
    unsigned short* __restrict__ Wt1, unsigned short* __restrict__ Wt2,
    float* __restrict__ bias1, float* __restrict__ bias2,
    int* __restrict__ cnt)
{
    int i = blockIdx.x * 256 + threadIdx.x;
    if (i < PREP_W0) {
        const float* src = (i < FEAT4) ? lf : rf;
        unsigned short* dst = (i < FEAT4) ? lfb : rfb;
        int j = (i < FEAT4) ? i : i - FEAT4;
        float4 v = ((const float4*)src)[j];
        ushort4 o;
        o.x = f2bf(v.x); o.y = f2bf(v.y); o.z = f2bf(v.z); o.w = f2bf(v.w);
        ((ushort4*)dst)[j] = o;
    } else if (i < PREP_W1) {
        int j = i - PREP_W0;
        if (j < 32768) {                       // Wt1: [256][128]
            int n = j >> 7, k = j & 127;
            float v = (k < 64) ? W1[(size_t)k * 256 + n] : W2[(size_t)(k - 64) * 256 + n];
            Wt1[j] = f2bf(v);
        } else if (j < 32768 + 65536) {        // Wt2: [128][512]
            int q = j - 32768;
            int n = q >> 9, k = q & 511;
            float v = (k < 256) ? W3[(size_t)k * 128 + n] : W4[(size_t)(k - 256) * 128 + n];
            Wt2[q] = f2bf(v);
        } else if (j < 98304 + 256) {
            int n = j - 98304; bias1[n] = b1[n] + b2[n];
        } else if (j < 98560 + 128) {
            int n = j - 98560; bias2[n] = b3[n] + b4[n];
        }
    } else if (i < PREP_Z) {
        int j = i - PREP_W1;
        ((int4*)cnt)[j] = make_int4(0, 0, 0, 0);
    }
}

// ---------------------------------------------------------------------------
// XCD-partitioned histogram: class = blockIdx&7 handles index range
// [class*PROWS, (class+1)*PROWS); each class strides the full edge list.
// ---------------------------------------------------------------------------
__global__ __launch_bounds__(256) void hist_part_kernel(
    const int* __restrict__ rows, const int* __restrict__ cols,
    int* __restrict__ rc, int* __restrict__ cc)
{
    int part = blockIdx.x & (NPART - 1);
    int lo = part * PROWS, hi = lo + PROWS;
    int nb = gridDim.x >> 3;
    int bj = blockIdx.x >> 3;
    int stride = nb * 256;
    for (int e = bj * 256 + threadIdx.x; e < NNZE; e += stride) {
        int r = rows[e];
        if (r >= lo && r < hi) atomicAdd(&rc[r], 1);
        int c = cols[e];
        if (c >= lo && c < hi) atomicAdd(&cc[c], 1);
    }
}

// ---------------------------------------------------------------------------
// hierarchical scan (3 phases); blocks 0..117 rows, 118..235 cols
// ---------------------------------------------------------------------------
#define SCB 118
__global__ __launch_bounds__(256) void scan_local_kernel(
    const int* __restrict__ rc, const int* __restrict__ cc,
    int* __restrict__ rf, int* __restrict__ cf, int* __restrict__ totals)
{
    int b = blockIdx.x;
    const int* cnt = (b < SCB) ? rc : cc;
    int*       esc = (b < SCB) ? rf : cf;
    int lb = (b < SCB) ? b : b - SCB;
    int t = threadIdx.x;
    int idx = lb * 256 + t;

    __shared__ int s[256];
    int v = (idx < NN) ? cnt[idx] : 0;
    s[t] = v;
    __syncthreads();
#pragma unroll
    for (int off = 1; off < 256; off <<= 1) {
        int u = (t >= off) ? s[t - off] : 0;
        __syncthreads();
        s[t] += u;
        __syncthreads();
    }
    if (idx < NN) esc[idx] = s[t] - v;       // exclusive
    if (t == 255) totals[b] = s[t];
}

__global__ __launch_bounds__(128) void scan_tot_kernel(int* __restrict__ totals)
{
    int base = blockIdx.x * SCB;
    int t = threadIdx.x;
    __shared__ int s[128];
    int v = (t < SCB) ? totals[base + t] : 0;
    s[t] = v;
    __syncthreads();
#pragma unroll
    for (int off = 1; off < 128; off <<= 1) {
        int u = (t >= off) ? s[t - off] : 0;
        __syncthreads();
        s[t] += u;
        __syncthreads();
    }
    if (t < SCB) totals[base + t] = s[t] - v;
}

__global__ __launch_bounds__(256) void scan_add_kernel(
    int* __restrict__ rf, int* __restrict__ cf,
    int* __restrict__ rp, int* __restrict__ cp,
    const int* __restrict__ totals)
{
    int b = blockIdx.x;
    int lb = (b < SCB) ? b : b - SCB;
    int t = threadIdx.x;
    int idx = lb * 256 + t;
    int off = totals[b];
    if (idx < NN) {
        if (b < SCB) { int v = rf[idx] + off; rp[idx] = v; rf[idx] = v; }
        else         { int v = cf[idx] + off; cp[idx] = v; cf[idx] = v; }
    }
    if (b == 0   && t == 0) rp[NN] = NNZE;
    if (b == SCB && t == 0) cp[NN] = NNZE;
}

// ---------------------------------------------------------------------------
// XCD-partitioned scatter into CSR/CSC order; (idx, valbits) packed int2.
// Class c writes only rows/cols in its 3750-wide range -> each destination
// cacheline is dirtied by one XCD only (kills the 8x write amplification).
// ---------------------------------------------------------------------------
__global__ __launch_bounds__(256) void scatter_part_kernel(
    const int* __restrict__ rows, const int* __restrict__ cols,
    const float* __restrict__ vals,
    int* __restrict__ rf, int* __restrict__ cf,
    int2* __restrict__ csr_pair, int2* __restrict__ csc_pair)
{
    int part = blockIdx.x & (NPART - 1);
    int lo = part * PROWS, hi = lo + PROWS;
    int nb = gridDim.x >> 3;
    int bj = blockIdx.x >> 3;
    int stride = nb * 256;
    for (int e = bj * 256 + threadIdx.x; e < NNZE; e += stride) {
        int r = rows[e], c = cols[e];
        int vb = __float_as_int(vals[e]);
        if (r >= lo && r < hi) {
            int p = atomicAdd(&rf[r], 1);
            csr_pair[p] = make_int2(c, vb);
        }
        if (c >= lo && c < hi) {
            int q = atomicAdd(&cf[c], 1);
            csc_pair[q] = make_int2(r, vb);
        }
    }
}

// ---------------------------------------------------------------------------
// gather-SpMM D=64 (both directions via blockIdx.y), bf16 feats:
//   acc = sum v*gf[idx]; X = [bf16(acc), bf16(acc*mf[w])]
// ---------------------------------------------------------------------------
__global__ __launch_bounds__(256) void gather64_x_kernel(
    const int* __restrict__ rp, const int2* __restrict__ rpair,
    const int* __restrict__ cp, const int2* __restrict__ cpair,
    const unsigned short* __restrict__ lfb, const unsigned short* __restrict__ rfb,
    unsigned short* __restrict__ X1, unsigned short* __restrict__ X2)
{
    int side = blockIdx.y;
    const int*  ptr  = side ? cp    : rp;
    const int2* pair = side ? cpair : rpair;
    const unsigned short* gf = side ? lfb : rfb;
    const unsigned short* mf = side ? rfb : lfb;
    unsigned short* X = side ? X2 : X1;

    int w    = blockIdx.x * 4 + (threadIdx.x >> 6);
    int lane = threadIdx.x & 63;
    int e0 = ptr[w], e1 = ptr[w + 1];
    float acc = 0.f;
    int e = e0;
    for (; e + 3 < e1; e += 4) {
        int2 p0 = pair[e],     p1 = pair[e + 1];
        int2 p2 = pair[e + 2], p3 = pair[e + 3];
        float f0 = bf2f(gf[(size_t)p0.x * 64 + lane]);
        float f1 = bf2f(gf[(size_t)p1.x * 64 + lane]);
        float f2 = bf2f(gf[(size_t)p2.x * 64 + lane]);
        float f3 = bf2f(gf[(size_t)p3.x * 64 + lane]);
        acc += __int_as_float(p0.y) * f0 + __int_as_float(p1.y) * f1
             + __int_as_float(p2.y) * f2 + __int_as_float(p3.y) * f3;
    }
    for (; e < e1; ++e) {
        int2 p0 = pair[e];
        acc += __int_as_float(p0.y) * bf2f(gf[(size_t)p0.x * 64 + lane]);
    }
    float m = acc * bf2f(mf[(size_t)w * 64 + lane]);
    X[(size_t)w * 128 + lane]      = f2bf(acc);
    X[(size_t)w * 128 + 64 + lane] = f2bf(m);
}

// ---------------------------------------------------------------------------
// gather-SpMM D=256, wave-per-row, bf16 z1, unroll-4:
//   acc[0..3] = sum v*z1b[idx]; X3 = [bf16(acc), bf16(acc*y1b[r])]
// ---------------------------------------------------------------------------
__global__ __launch_bounds__(256) void gather256_x_kernel(
    const int* __restrict__ ptr, const int2* __restrict__ pair,
    const unsigned short* __restrict__ z1b, const unsigned short* __restrict__ y1b,
    unsigned short* __restrict__ X3)
{
    int w    = blockIdx.x * 4 + (threadIdx.x >> 6);
    int lane = threadIdx.x & 63;
    int e0 = ptr[w], e1 = ptr[w + 1];
    const ushort4* Z = (const ushort4*)z1b;   // row stride 64 ushort4
    f4 acc = {0.f, 0.f, 0.f, 0.f};
    int e = e0;
    for (; e + 3 < e1; e += 4) {
        int2 p0 = pair[e],     p1 = pair[e + 1];
        int2 p2 = pair[e + 2], p3 = pair[e + 3];
        ushort4 z0 = Z[(size_t)p0.x * 64 + lane];
        ushort4 z1 = Z[(size_t)p1.x * 64 + lane];
        ushort4 z2 = Z[(size_t)p2.x * 64 + lane];
        ushort4 z3 = Z[(size_t)p3.x * 64 + lane];
        float v0 = __int_as_float(p0.y), v1 = __int_as_float(p1.y);
        float v2 = __int_as_float(p2.y), v3 = __int_as_float(p3.y);
        acc[0] += v0 * bf2f(z0.x) + v1 * bf2f(z1.x) + v2 * bf2f(z2.x) + v3 * bf2f(z3.x);
        acc[1] += v0 * bf2f(z0.y) + v1 * bf2f(z1.y) + v2 * bf2f(z2.y) + v3 * bf2f(z3.y);
        acc[2] += v0 * bf2f(z0.z) + v1 * bf2f(z1.z) + v2 * bf2f(z2.z) + v3 * bf2f(z3.z);
        acc[3] += v0 * bf2f(z0.w) + v1 * bf2f(z1.w) + v2 * bf2f(z2.w) + v3 * bf2f(z3.w);
    }
    for (; e < e1; ++e) {
        int2 p0 = pair[e];
        float v0 = __int_as_float(p0.y);
        ushort4 z0 = Z[(size_t)p0.x * 64 + lane];
        acc[0] += v0 * bf2f(z0.x);
        acc[1] += v0 * bf2f(z0.y);
        acc[2] += v0 * bf2f(z0.z);
        acc[3] += v0 * bf2f(z0.w);
    }
    ushort4 y = ((const ushort4*)y1b)[(size_t)w * 64 + lane];
    ushort4 o0, o1;
    o0.x = f2bf(acc[0]); o0.y = f2bf(acc[1]); o0.z = f2bf(acc[2]); o0.w = f2bf(acc[3]);
    o1.x = f2bf(acc[0] * bf2f(y.x));
    o1.y = f2bf(acc[1] * bf2f(y.y));
    o1.z = f2bf(acc[2] * bf2f(y.z));
    o1.w = f2bf(acc[3] * bf2f(y.w));
    ((ushort4*)X3)[(size_t)w * 128 + lane]      = o0;
    ((ushort4*)X3)[(size_t)w * 128 + 64 + lane] = o1;
}

// ---------------------------------------------------------------------------
// MFMA GEMM: out = relu(X[NN][K] @ Wt^T + bias), Wt [DOUT][K] bf16.
// Dual-input: blockIdx.y selects (Xa->outa) or (Xb->outb), sharing Wt.
// Block: 4 waves, tile 64 rows x DOUT cols. K chunks of 64; LDS XOR-swizzled.
// ---------------------------------------------------------------------------
template<int K, int DOUT, bool OUT_BF16>
__global__ __launch_bounds__(256) void mfma_gemm_kernel(
    const unsigned short* Xa, const unsigned short* Xb,
    const unsigned short* __restrict__ Wt, const float* __restrict__ bias,
    void* outa, void* outb)
{
    constexpr int WC = DOUT / 4;       // cols per wave (64 or 32)
    constexpr int FN = WC / 16;        // 4 or 2
    __shared__ s8 sX[64 * 8];          // [row][chunk], chunk ^= row&7
    __shared__ s8 sW[DOUT * 8];

    const unsigned short* X = blockIdx.y ? Xb : Xa;
    void* outv              = blockIdx.y ? outb : outa;

    const int t       = threadIdx.x;
    const int rowbase = blockIdx.x * 64;
    const int wid     = t >> 6;
    const int lane    = t & 63;
    const int l15     = lane & 15;
    const int kg      = lane >> 4;

    f4 acc[4][FN] = {};

    for (int kc = 0; kc < K; kc += 64) {
#pragma unroll
        for (int it = 0; it < 2; ++it) {
            int ch = t + it * 256;
            int r = ch >> 3, c = ch & 7;
            int row = rowbase + r;
            s8 v = {};
            if (row < NN) v = ((const s8*)X)[((size_t)row * K + kc) / 8 + c];
            sX[(r << 3) | (c ^ (r & 7))] = v;
        }
#pragma unroll
        for (int it = 0; it < DOUT / 32; ++it) {
            int ch = t + it * 256;
            int n = ch >> 3, c = ch & 7;
            sW[(n << 3) | (c ^ (n & 7))] = ((const s8*)Wt)[((size_t)n * K + kc) / 8 + c];
        }
        __syncthreads();

#pragma unroll
        for (int ks = 0; ks < 2; ++ks) {
            int cch = ks * 4 + kg;
            s8 a[4], b[FN];
#pragma unroll
            for (int fm = 0; fm < 4; ++fm) {
                int r0 = fm * 16 + l15;
                a[fm] = sX[(r0 << 3) | (cch ^ (r0 & 7))];
            }
#pragma unroll
            for (int fn = 0; fn < FN; ++fn) {
                int n0 = wid * WC + fn * 16 + l15;
                b[fn] = sW[(n0 << 3) | (cch ^ (n0 & 7))];
            }
#pragma unroll
            for (int fm = 0; fm < 4; ++fm)
#pragma unroll
                for (int fn = 0; fn < FN; ++fn)
                    acc[fm][fn] = __builtin_amdgcn_mfma_f32_16x16x32_bf16(
                        a[fm], b[fn], acc[fm][fn], 0, 0, 0);
        }
        __syncthreads();
    }

    // epilogue: C/D layout col=lane&15, row=kg*4+j
#pragma unroll
    for (int fm = 0; fm < 4; ++fm) {
#pragma unroll
        for (int fn = 0; fn < FN; ++fn) {
            int col = wid * WC + fn * 16 + l15;
            float bv = bias[col];
#pragma unroll
            for (int j = 0; j < 4; ++j) {
                int row = rowbase + fm * 16 + kg * 4 + j;
                if (row < NN) {
                    float v = fmaxf(acc[fm][fn][j] + bv, 0.f);
                    if constexpr (OUT_BF16)
                        ((unsigned short*)outv)[(size_t)row * DOUT + col] = f2bf(v);
                    else
                        ((float*)outv)[(size_t)row * DOUT + col] = v;
                }
            }
        }
    }
}

// ---------------------------------------------------------------------------
extern "C" void kernel_launch(void* const* d_in, const int* in_sizes, int n_in,
                              void* d_out, int out_size, void* d_ws, size_t ws_size,
                              hipStream_t stream)
{
    const float* l_feat = (const float*)d_in[0];
    const float* r_feat = (const float*)d_in[1];
    const int*   rows   = (const int*)  d_in[2];
    const int*   cols   = (const int*)  d_in[3];
    const float* vals   = (const float*)d_in[4];
    const float* W1     = (const float*)d_in[5];
    const float* b1     = (const float*)d_in[6];
    const float* W2     = (const float*)d_in[7];
    const float* b2     = (const float*)d_in[8];
    const float* W3     = (const float*)d_in[9];
    const float* b3     = (const float*)d_in[10];
    const float* W4     = (const float*)d_in[11];
    const float* b4     = (const float*)d_in[12];
    float* out = (float*)d_out;

    // ---- workspace carve ----
    char* p = (char*)d_ws;
    unsigned short* X1  = (unsigned short*)p; p += (size_t)NN * 128 * 2;
    unsigned short* X2  = (unsigned short*)p; p += (size_t)NN * 128 * 2;
    unsigned short* X3  = (unsigned short*)p; p += (size_t)NN * 512 * 2;
    unsigned short* z1b = (unsigned short*)p; p += (size_t)NN * 256 * 2;
    unsigned short* y1b = (unsigned short*)p; p += (size_t)NN * 256 * 2;
    unsigned short* lfb = (unsigned short*)p; p += (size_t)NN * 64 * 2;
    unsigned short* rfb = (unsigned short*)p; p += (size_t)NN * 64 * 2;
    int* row_cnt  = (int*)p; p += (size_t)NN * 4;
    int* col_cnt  = (int*)p; p += (size_t)NN * 4;
    int* row_fill = (int*)p; p += (size_t)NN * 4;
    int* col_fill = (int*)p; p += (size_t)NN * 4;
    int* totals   = (int*)p; p += 256 * 4;
    unsigned short* Wt1 = (unsigned short*)p; p += 32768 * 2;
    unsigned short* Wt2 = (unsigned short*)p; p += 65536 * 2;
    float* bias1 = (float*)p; p += 256 * 4;
    float* bias2 = (float*)p; p += 128 * 4;
    int*   row_ptr  = (int*)p; p += (size_t)(NN + 4) * 4;
    int*   col_ptr  = (int*)p; p += (size_t)(NN + 4) * 4;
    int2*  csr_pair = (int2*)p; p += (size_t)NNZE * 8;
    int2*  csc_pair = (int2*)p; p += (size_t)NNZE * 8;

    // 1. fused prep: feats->bf16, weight transpose, bias sums, zero counters
    prep_kernel<<<(PREP_Z + 255) / 256, 256, 0, stream>>>(
        l_feat, r_feat, W1, W2, W3, W4, b1, b2, b3, b4,
        lfb, rfb, Wt1, Wt2, bias1, bias2, row_cnt);

    // 2. XCD-partitioned histogram
    hist_part_kernel<<<1024, 256, 0, stream>>>(rows, cols, row_cnt, col_cnt);

    // 3. hierarchical scan
    scan_local_kernel<<<2 * SCB, 256, 0, stream>>>(row_cnt, col_cnt, row_fill, col_fill, totals);
    scan_tot_kernel<<<2, 128, 0, stream>>>(totals);
    scan_add_kernel<<<2 * SCB, 256, 0, stream>>>(row_fill, col_fill, row_ptr, col_ptr, totals);

    // 4. XCD-partitioned scatter into CSR + CSC order
    scatter_part_kernel<<<1024, 256, 0, stream>>>(
        rows, cols, vals, row_fill, col_fill, csr_pair, csc_pair);

    // 5. gather-SpMM D=64, both directions in one launch
    {
        dim3 grid(NN / 4, 2);
        gather64_x_kernel<<<grid, 256, 0, stream>>>(
            row_ptr, csr_pair, col_ptr, csc_pair, lfb, rfb, X1, X2);
    }

    // 6. layer-1 MFMA GEMMs, both sides in one launch (shared Wt1)
    {
        dim3 grid((NN + 63) / 64, 2);
        mfma_gemm_kernel<128, 256, true><<<grid, 256, 0, stream>>>(
            X1, X2, Wt1, bias1, y1b, z1b);
    }

    // 7. gather-SpMM D=256 (bf16 z1), fused layer-2 input prep
    gather256_x_kernel<<<NN / 4, 256, 0, stream>>>(row_ptr, csr_pair, z1b, y1b, X3);

    // 8. layer-2 MFMA GEMM -> output (f32)
    {
        dim3 grid((NN + 63) / 64, 1);
        mfma_gemm_kernel<512, 128, false><<<grid, 256, 0, stream>>>(
            X3, X3, Wt2, bias2, out, out);
    }
}

// Round 6
// 211.232 us; speedup vs baseline: 3.5347x; 1.0516x over previous
//
#include <hip/hip_runtime.h>

#define NN    30000
#define NNZE  480000
#define NPART 8
#define PROWS (NN / NPART)     // 3750, exact

using s8 = __attribute__((ext_vector_type(8))) short;  // 8 bf16 = 4 VGPRs
using f4 = __attribute__((ext_vector_type(4))) float;

__device__ __forceinline__ unsigned short f2bf(float x) {
    unsigned int u = __float_as_uint(x);
    u += 0x7fff + ((u >> 16) & 1);          // round-to-nearest-even
    return (unsigned short)(u >> 16);
}
__device__ __forceinline__ float bf2f(unsigned short h) {
    return __uint_as_float(((unsigned int)h) << 16);
}
__device__ __forceinline__ float bflo(unsigned int z) {
    return __uint_as_float(z << 16);
}
__device__ __forceinline__ float bfhi(unsigned int z) {
    return __uint_as_float(z & 0xffff0000u);
}
__device__ __forceinline__ int2 nt_pair(const int2* p) {
    long long v = __builtin_nontemporal_load((const long long*)p);
    int2 r; r.x = (int)(unsigned int)v; r.y = (int)(v >> 32); return r;
}

// ---------------------------------------------------------------------------
// fused prep: feat->bf16 conversion, weight transpose->bf16, bias sums,
// and zeroing of the 2*NN histogram counters
// ---------------------------------------------------------------------------
#define FEAT4   (NN * 64 / 4)              // 480000 float4 groups per feat
#define PREP_W0 (2 * FEAT4)                // 960000
#define PREP_W1 (PREP_W0 + 98688)          // wprep range
#define PREP_Z  (PREP_W1 + 2 * NN / 4)     // zero range (int4)
__global__ __launch_bounds__(256) void prep_kernel(
    const float* __restrict__ lf, const float* __restrict__ rf,
    const float* __restrict__ W1, const float* __restrict__ W2,
    const float* __restrict__ W3, const float* __restrict__ W4,
    const float* __restrict__ b1, const float* __restrict__ b2,
    const float* __restrict__ b3, const float* __restrict__ b4,
    unsigned short* __restrict__ lfb, unsigned short* __restrict__ rfb,
    unsigned short* __restrict__ Wt1, unsigned short* __restrict__ Wt2,
    float* __restrict__ bias1, float* __restrict__ bias2,
    int* __restrict__ cnt)
{
    int i = blockIdx.x * 256 + threadIdx.x;
    if (i < PREP_W0) {
        const float* src = (i < FEAT4) ? lf : rf;
        unsigned short* dst = (i < FEAT4) ? lfb : rfb;
        int j = (i < FEAT4) ? i : i - FEAT4;
        float4 v = ((const float4*)src)[j];
        ushort4 o;
        o.x = f2bf(v.x); o.y = f2bf(v.y); o.z = f2bf(v.z); o.w = f2bf(v.w);
        ((ushort4*)dst)[j] = o;
    } else if (i < PREP_W1) {
        int j = i - PREP_W0;
        if (j < 32768) {                       // Wt1: [256][128]
            int n = j >> 7, k = j & 127;
            float v = (k < 64) ? W1[(size_t)k * 256 + n] : W2[(size_t)(k - 64) * 256 + n];
            Wt1[j] = f2bf(v);
        } else if (j < 32768 + 65536) {        // Wt2: [128][512]
            int q = j - 32768;
            int n = q >> 9, k = q & 511;
            float v = (k < 256) ? W3[(size_t)k * 128 + n] : W4[(size_t)(k - 256) * 128 + n];
            Wt2[q] = f2bf(v);
        } else if (j < 98304 + 256) {
            int n = j - 98304; bias1[n] = b1[n] + b2[n];
        } else if (j < 98560 + 128) {
            int n = j - 98560; bias2[n] = b3[n] + b4[n];
        }
    } else if (i < PREP_Z) {
        int j = i - PREP_W1;
        ((int4*)cnt)[j] = make_int4(0, 0, 0, 0);
    }
}

// ---------------------------------------------------------------------------
// XCD-partitioned histogram, non-temporal edge reads
// ---------------------------------------------------------------------------
__global__ __launch_bounds__(256) void hist_part_kernel(
    const int* __restrict__ rows, const int* __restrict__ cols,
    int* __restrict__ rc, int* __restrict__ cc)
{
    int part = blockIdx.x & (NPART - 1);
    int lo = part * PROWS, hi = lo + PROWS;
    int nb = gridDim.x >> 3;
    int bj = blockIdx.x >> 3;
    int stride = nb * 256;
    for (int e = bj * 256 + threadIdx.x; e < NNZE; e += stride) {
        int r = __builtin_nontemporal_load(rows + e);
        if (r >= lo && r < hi) atomicAdd(&rc[r], 1);
        int c = __builtin_nontemporal_load(cols + e);
        if (c >= lo && c < hi) atomicAdd(&cc[c], 1);
    }
}

// ---------------------------------------------------------------------------
// hierarchical scan (3 phases); blocks 0..117 rows, 118..235 cols
// ---------------------------------------------------------------------------
#define SCB 118
__global__ __launch_bounds__(256) void scan_local_kernel(
    const int* __restrict__ rc, const int* __restrict__ cc,
    int* __restrict__ rf, int* __restrict__ cf, int* __restrict__ totals)
{
    int b = blockIdx.x;
    const int* cnt = (b < SCB) ? rc : cc;
    int*       esc = (b < SCB) ? rf : cf;
    int lb = (b < SCB) ? b : b - SCB;
    int t = threadIdx.x;
    int idx = lb * 256 + t;

    __shared__ int s[256];
    int v = (idx < NN) ? cnt[idx] : 0;
    s[t] = v;
    __syncthreads();
#pragma unroll
    for (int off = 1; off < 256; off <<= 1) {
        int u = (t >= off) ? s[t - off] : 0;
        __syncthreads();
        s[t] += u;
        __syncthreads();
    }
    if (idx < NN) esc[idx] = s[t] - v;       // exclusive
    if (t == 255) totals[b] = s[t];
}

__global__ __launch_bounds__(128) void scan_tot_kernel(int* __restrict__ totals)
{
    int base = blockIdx.x * SCB;
    int t = threadIdx.x;
    __shared__ int s[128];
    int v = (t < SCB) ? totals[base + t] : 0;
    s[t] = v;
    __syncthreads();
#pragma unroll
    for (int off = 1; off < 128; off <<= 1) {
        int u = (t >= off) ? s[t - off] : 0;
        __syncthreads();
        s[t] += u;
        __syncthreads();
    }
    if (t < SCB) totals[base + t] = s[t] - v;
}

__global__ __launch_bounds__(256) void scan_add_kernel(
    int* __restrict__ rf, int* __restrict__ cf,
    int* __restrict__ rp, int* __restrict__ cp,
    const int* __restrict__ totals)
{
    int b = blockIdx.x;
    int lb = (b < SCB) ? b : b - SCB;
    int t = threadIdx.x;
    int idx = lb * 256 + t;
    int off = totals[b];
    if (idx < NN) {
        if (b < SCB) { int v = rf[idx] + off; rp[idx] = v; rf[idx] = v; }
        else         { int v = cf[idx] + off; cp[idx] = v; cf[idx] = v; }
    }
    if (b == 0   && t == 0) rp[NN] = NNZE;
    if (b == SCB && t == 0) cp[NN] = NNZE;
}

// ---------------------------------------------------------------------------
// XCD-partitioned scatter, non-temporal edge reads (keeps the dirty CSR/CSC
// destination lines resident in the class's L2 until fully filled)
// ---------------------------------------------------------------------------
__global__ __launch_bounds__(256) void scatter_part_kernel(
    const int* __restrict__ rows, const int* __restrict__ cols,
    const float* __restrict__ vals,
    int* __restrict__ rf, int* __restrict__ cf,
    int2* __restrict__ csr_pair, int2* __restrict__ csc_pair)
{
    int part = blockIdx.x & (NPART - 1);
    int lo = part * PROWS, hi = lo + PROWS;
    int nb = gridDim.x >> 3;
    int bj = blockIdx.x >> 3;
    int stride = nb * 256;
    for (int e = bj * 256 + threadIdx.x; e < NNZE; e += stride) {
        int r = __builtin_nontemporal_load(rows + e);
        int c = __builtin_nontemporal_load(cols + e);
        float fv = __builtin_nontemporal_load(vals + e);
        int vb = __float_as_int(fv);
        if (r >= lo && r < hi) {
            int p = atomicAdd(&rf[r], 1);
            csr_pair[p] = make_int2(c, vb);
        }
        if (c >= lo && c < hi) {
            int q = atomicAdd(&cf[c], 1);
            csc_pair[q] = make_int2(r, vb);
        }
    }
}

// ---------------------------------------------------------------------------
// gather-SpMM D=64: half-wave (32 lanes) per row, lane owns 2 features
// (packed uint of 2 bf16). Unroll-8 for 8 outstanding gathers.
//   acc = sum v*gf[idx]; X = [bf16(acc), bf16(acc*mf[w])]
// ---------------------------------------------------------------------------
__global__ __launch_bounds__(256) void gather64_x_kernel(
    const int* __restrict__ rp, const int2* __restrict__ rpair,
    const int* __restrict__ cp, const int2* __restrict__ cpair,
    const unsigned short* __restrict__ lfb, const unsigned short* __restrict__ rfb,
    unsigned short* __restrict__ X1, unsigned short* __restrict__ X2)
{
    int side = blockIdx.y;
    const int*  ptr  = side ? cp    : rp;
    const int2* pair = side ? cpair : rpair;
    const unsigned int* gf = (const unsigned int*)(side ? lfb : rfb);
    const unsigned int* mf = (const unsigned int*)(side ? rfb : lfb);
    unsigned int* X = (unsigned int*)(side ? X2 : X1);

    int w = blockIdx.x * 8 + (threadIdx.x >> 5);   // half-wave per row
    int l = threadIdx.x & 31;
    int e0 = ptr[w], e1 = ptr[w + 1];
    float a0 = 0.f, a1 = 0.f;
    int e = e0;
    for (; e + 7 < e1; e += 8) {
        int2 p[8];
#pragma unroll
        for (int j = 0; j < 8; ++j) p[j] = nt_pair(&pair[e + j]);
        unsigned int z[8];
#pragma unroll
        for (int j = 0; j < 8; ++j) z[j] = gf[(size_t)p[j].x * 32 + l];
#pragma unroll
        for (int j = 0; j < 8; ++j) {
            float v = __int_as_float(p[j].y);
            a0 += v * bflo(z[j]);
            a1 += v * bfhi(z[j]);
        }
    }
    for (; e < e1; ++e) {
        int2 p0 = nt_pair(&pair[e]);
        unsigned int z0 = gf[(size_t)p0.x * 32 + l];
        float v = __int_as_float(p0.y);
        a0 += v * bflo(z0);
        a1 += v * bfhi(z0);
    }
    unsigned int m = mf[(size_t)w * 32 + l];
    float m0 = a0 * bflo(m);
    float m1 = a1 * bfhi(m);
    X[(size_t)w * 64 + l]      = (unsigned int)f2bf(a0) | ((unsigned int)f2bf(a1) << 16);
    X[(size_t)w * 64 + 32 + l] = (unsigned int)f2bf(m0) | ((unsigned int)f2bf(m1) << 16);
}

// ---------------------------------------------------------------------------
// gather-SpMM D=256, wave-per-row, bf16 z1, unroll-8:
//   acc[0..3] = sum v*z1b[idx]; X3 = [bf16(acc), bf16(acc*y1b[r])]
// ---------------------------------------------------------------------------
__global__ __launch_bounds__(256) void gather256_x_kernel(
    const int* __restrict__ ptr, const int2* __restrict__ pair,
    const unsigned short* __restrict__ z1b, const unsigned short* __restrict__ y1b,
    unsigned short* __restrict__ X3)
{
    int w    = blockIdx.x * 4 + (threadIdx.x >> 6);
    int lane = threadIdx.x & 63;
    int e0 = ptr[w], e1 = ptr[w + 1];
    const ushort4* Z = (const ushort4*)z1b;   // row stride 64 ushort4
    f4 acc = {0.f, 0.f, 0.f, 0.f};
    int e = e0;
    for (; e + 7 < e1; e += 8) {
        int2 p[8];
#pragma unroll
        for (int j = 0; j < 8; ++j) p[j] = nt_pair(&pair[e + j]);
        ushort4 z[8];
#pragma unroll
        for (int j = 0; j < 8; ++j) z[j] = Z[(size_t)p[j].x * 64 + lane];
#pragma unroll
        for (int j = 0; j < 8; ++j) {
            float v = __int_as_float(p[j].y);
            acc[0] += v * bf2f(z[j].x);
            acc[1] += v * bf2f(z[j].y);
            acc[2] += v * bf2f(z[j].z);
            acc[3] += v * bf2f(z[j].w);
        }
    }
    for (; e < e1; ++e) {
        int2 p0 = nt_pair(&pair[e]);
        float v0 = __int_as_float(p0.y);
        ushort4 z0 = Z[(size_t)p0.x * 64 + lane];
        acc[0] += v0 * bf2f(z0.x);
        acc[1] += v0 * bf2f(z0.y);
        acc[2] += v0 * bf2f(z0.z);
        acc[3] += v0 * bf2f(z0.w);
    }
    ushort4 y = ((const ushort4*)y1b)[(size_t)w * 64 + lane];
    ushort4 o0, o1;
    o0.x = f2bf(acc[0]); o0.y = f2bf(acc[1]); o0.z = f2bf(acc[2]); o0.w = f2bf(acc[3]);
    o1.x = f2bf(acc[0] * bf2f(y.x));
    o1.y = f2bf(acc[1] * bf2f(y.y));
    o1.z = f2bf(acc[2] * bf2f(y.z));
    o1.w = f2bf(acc[3] * bf2f(y.w));
    ((ushort4*)X3)[(size_t)w * 128 + lane]      = o0;
    ((ushort4*)X3)[(size_t)w * 128 + 64 + lane] = o1;
}

// ---------------------------------------------------------------------------
// MFMA GEMM: out = relu(X[NN][K] @ Wt^T + bias), Wt [DOUT][K] bf16.
// Dual-input: blockIdx.y selects (Xa->outa) or (Xb->outb), sharing Wt.
// Block: 4 waves, tile 64 rows x DOUT cols. K chunks of 64; LDS XOR-swizzled.
// ---------------------------------------------------------------------------
template<int K, int DOUT, bool OUT_BF16>
__global__ __launch_bounds__(256) void mfma_gemm_kernel(
    const unsigned short* Xa, const unsigned short* Xb,
    const unsigned short* __restrict__ Wt, const float* __restrict__ bias,
    void* outa, void* outb)
{
    constexpr int WC = DOUT / 4;       // cols per wave (64 or 32)
    constexpr int FN = WC / 16;        // 4 or 2
    __shared__ s8 sX[64 * 8];          // [row][chunk], chunk ^= row&7
    __shared__ s8 sW[DOUT * 8];

    const unsigned short* X = blockIdx.y ? Xb : Xa;
    void* outv              = blockIdx.y ? outb : outa;

    const int t       = threadIdx.x;
    const int rowbase = blockIdx.x * 64;
    const int wid     = t >> 6;
    const int lane    = t & 63;
    const int l15     = lane & 15;
    const int kg      = lane >> 4;

    f4 acc[4][FN] = {};

    for (int kc = 0; kc < K; kc += 64) {
#pragma unroll
        for (int it = 0; it < 2; ++it) {
            int ch = t + it * 256;
            int r = ch >> 3, c = ch & 7;
            int row = rowbase + r;
            s8 v = {};
            if (row < NN) v = ((const s8*)X)[((size_t)row * K + kc) / 8 + c];
            sX[(r << 3) | (c ^ (r & 7))] = v;
        }
#pragma unroll
        for (int it = 0; it < DOUT / 32; ++it) {
            int ch = t + it * 256;
            int n = ch >> 3, c = ch & 7;
            sW[(n << 3) | (c ^ (n & 7))] = ((const s8*)Wt)[((size_t)n * K + kc) / 8 + c];
        }
        __syncthreads();

#pragma unroll
        for (int ks = 0; ks < 2; ++ks) {
            int cch = ks * 4 + kg;
            s8 a[4], b[FN];
#pragma unroll
            for (int fm = 0; fm < 4; ++fm) {
                int r0 = fm * 16 + l15;
                a[fm] = sX[(r0 << 3) | (cch ^ (r0 & 7))];
            }
#pragma unroll
            for (int fn = 0; fn < FN; ++fn) {
                int n0 = wid * WC + fn * 16 + l15;
                b[fn] = sW[(n0 << 3) | (cch ^ (n0 & 7))];
            }
#pragma unroll
            for (int fm = 0; fm < 4; ++fm)
#pragma unroll
                for (int fn = 0; fn < FN; ++fn)
                    acc[fm][fn] = __builtin_amdgcn_mfma_f32_16x16x32_bf16(
                        a[fm], b[fn], acc[fm][fn], 0, 0, 0);
        }
        __syncthreads();
    }

    // epilogue: C/D layout col=lane&15, row=kg*4+j
#pragma unroll
    for (int fm = 0; fm < 4; ++fm) {
#pragma unroll
        for (int fn = 0; fn < FN; ++fn) {
            int col = wid * WC + fn * 16 + l15;
            float bv = bias[col];
#pragma unroll
            for (int j = 0; j < 4; ++j) {
                int row = rowbase + fm * 16 + kg * 4 + j;
                if (row < NN) {
                    float v = fmaxf(acc[fm][fn][j] + bv, 0.f);
                    if constexpr (OUT_BF16)
                        ((unsigned short*)outv)[(size_t)row * DOUT + col] = f2bf(v);
                    else
                        ((float*)outv)[(size_t)row * DOUT + col] = v;
                }
            }
        }
    }
}

// ---------------------------------------------------------------------------
extern "C" void kernel_launch(void* const* d_in, const int* in_sizes, int n_in,
                              void* d_out, int out_size, void* d_ws, size_t ws_size,
                              hipStream_t stream)
{
    const float* l_feat = (const float*)d_in[0];
    const float* r_feat = (const float*)d_in[1];
    const int*   rows   = (const int*)  d_in[2];
    const int*   cols   = (const int*)  d_in[3];
    const float* vals   = (const float*)d_in[4];
    const float* W1     = (const float*)d_in[5];
    const float* b1     = (const float*)d_in[6];
    const float* W2     = (const float*)d_in[7];
    const float* b2     = (const float*)d_in[8];
    const float* W3     = (const float*)d_in[9];
    const float* b3     = (const float*)d_in[10];
    const float* W4     = (const float*)d_in[11];
    const float* b4     = (const float*)d_in[12];
    float* out = (float*)d_out;

    // ---- workspace carve ----
    char* p = (char*)d_ws;
    unsigned short* X1  = (unsigned short*)p; p += (size_t)NN * 128 * 2;
    unsigned short* X2  = (unsigned short*)p; p += (size_t)NN * 128 * 2;
    unsigned short* X3  = (unsigned short*)p; p += (size_t)NN * 512 * 2;
    unsigned short* z1b = (unsigned short*)p; p += (size_t)NN * 256 * 2;
    unsigned short* y1b = (unsigned short*)p; p += (size_t)NN * 256 * 2;
    unsigned short* lfb = (unsigned short*)p; p += (size_t)NN * 64 * 2;
    unsigned short* rfb = (unsigned short*)p; p += (size_t)NN * 64 * 2;
    int* row_cnt  = (int*)p; p += (size_t)NN * 4;
    int* col_cnt  = (int*)p; p += (size_t)NN * 4;
    int* row_fill = (int*)p; p += (size_t)NN * 4;
    int* col_fill = (int*)p; p += (size_t)NN * 4;
    int* totals   = (int*)p; p += 256 * 4;
    unsigned short* Wt1 = (unsigned short*)p; p += 32768 * 2;
    unsigned short* Wt2 = (unsigned short*)p; p += 65536 * 2;
    float* bias1 = (float*)p; p += 256 * 4;
    float* bias2 = (float*)p; p += 128 * 4;
    int*   row_ptr  = (int*)p; p += (size_t)(NN + 4) * 4;
    int*   col_ptr  = (int*)p; p += (size_t)(NN + 4) * 4;
    int2*  csr_pair = (int2*)p; p += (size_t)NNZE * 8;
    int2*  csc_pair = (int2*)p; p += (size_t)NNZE * 8;

    // 1. fused prep: feats->bf16, weight transpose, bias sums, zero counters
    prep_kernel<<<(PREP_Z + 255) / 256, 256, 0, stream>>>(
        l_feat, r_feat, W1, W2, W3, W4, b1, b2, b3, b4,
        lfb, rfb, Wt1, Wt2, bias1, bias2, row_cnt);

    // 2. XCD-partitioned histogram
    hist_part_kernel<<<1024, 256, 0, stream>>>(rows, cols, row_cnt, col_cnt);

    // 3. hierarchical scan
    scan_local_kernel<<<2 * SCB, 256, 0, stream>>>(row_cnt, col_cnt, row_fill, col_fill, totals);
    scan_tot_kernel<<<2, 128, 0, stream>>>(totals);
    scan_add_kernel<<<2 * SCB, 256, 0, stream>>>(row_fill, col_fill, row_ptr, col_ptr, totals);

    // 4. XCD-partitioned scatter into CSR + CSC order
    scatter_part_kernel<<<1024, 256, 0, stream>>>(
        rows, cols, vals, row_fill, col_fill, csr_pair, csc_pair);

    // 5. gather-SpMM D=64, both directions in one launch (half-wave per row)
    {
        dim3 grid(NN / 8, 2);
        gather64_x_kernel<<<grid, 256, 0, stream>>>(
            row_ptr, csr_pair, col_ptr, csc_pair, lfb, rfb, X1, X2);
    }

    // 6. layer-1 MFMA GEMMs, both sides in one launch (shared Wt1)
    {
        dim3 grid((NN + 63) / 64, 2);
        mfma_gemm_kernel<128, 256, true><<<grid, 256, 0, stream>>>(
            X1, X2, Wt1, bias1, y1b, z1b);
    }

    // 7. gather-SpMM D=256 (bf16 z1), fused layer-2 input prep
    gather256_x_kernel<<<NN / 4, 256, 0, stream>>>(row_ptr, csr_pair, z1b, y1b, X3);

    // 8. layer-2 MFMA GEMM -> output (f32)
    {
        dim3 grid((NN + 63) / 64, 1);
        mfma_gemm_kernel<512, 128, false><<<grid, 256, 0, stream>>>(
            X3, X3, Wt2, bias2, out, out);
    }
}

// Round 7
// 199.689 us; speedup vs baseline: 3.7391x; 1.0578x over previous
//
#include <hip/hip_runtime.h>

#define NN    30000
#define NNZE  480000
#define NPART 8
#define PROWS (NN / NPART)     // 3750, exact

using s8 = __attribute__((ext_vector_type(8))) short;  // 8 bf16 = 4 VGPRs
using f4 = __attribute__((ext_vector_type(4))) float;

__device__ __forceinline__ unsigned short f2bf(float x) {
    unsigned int u = __float_as_uint(x);
    u += 0x7fff + ((u >> 16) & 1);          // round-to-nearest-even
    return (unsigned short)(u >> 16);
}
__device__ __forceinline__ float bf2f(unsigned short h) {
    return __uint_as_float(((unsigned int)h) << 16);
}
__device__ __forceinline__ float bflo(unsigned int z) {
    return __uint_as_float(z << 16);
}
__device__ __forceinline__ float bfhi(unsigned int z) {
    return __uint_as_float(z & 0xffff0000u);
}
__device__ __forceinline__ int2 nt_pair(const int2* p) {
    long long v = __builtin_nontemporal_load((const long long*)p);
    int2 r; r.x = (int)(unsigned int)v; r.y = (int)(v >> 32); return r;
}

// ---------------------------------------------------------------------------
// fused prep: feat->bf16 conversion, weight transpose->bf16, bias sums,
// and zeroing of the 2*NN histogram counters
// ---------------------------------------------------------------------------
#define FEAT4   (NN * 64 / 4)              // 480000 float4 groups per feat
#define PREP_W0 (2 * FEAT4)                // 960000
#define PREP_W1 (PREP_W0 + 98688)          // wprep range
#define PREP_Z  (PREP_W1 + 2 * NN / 4)     // zero range (int4)
__global__ __launch_bounds__(256) void prep_kernel(
    const float* __restrict__ lf, const float* __restrict__ rf,
    const float* __restrict__ W1, const float* __restrict__ W2,
    const float* __restrict__ W3, const float* __restrict__ W4,
    const float* __restrict__ b1, const float* __restrict__ b2,
    const float* __restrict__ b3, const float* __restrict__ b4,
    unsigned short* __restrict__ lfb, unsigned short* __restrict__ rfb,
    unsigned short* __restrict__ Wt1, unsigned short* __restrict__ Wt2,
    float* __restrict__ bias1, float* __restrict__ bias2,
    int* __restrict__ cnt)
{
    int i = blockIdx.x * 256 + threadIdx.x;
    if (i < PREP_W0) {
        const float* src = (i < FEAT4) ? lf : rf;
        unsigned short* dst = (i < FEAT4) ? lfb : rfb;
        int j = (i < FEAT4) ? i : i - FEAT4;
        float4 v = ((const float4*)src)[j];
        ushort4 o;
        o.x = f2bf(v.x); o.y = f2bf(v.y); o.z = f2bf(v.z); o.w = f2bf(v.w);
        ((ushort4*)dst)[j] = o;
    } else if (i < PREP_W1) {
        int j = i - PREP_W0;
        if (j < 32768) {                       // Wt1: [256][128]
            int n = j >> 7, k = j & 127;
            float v = (k < 64) ? W1[(size_t)k * 256 + n] : W2[(size_t)(k - 64) * 256 + n];
            Wt1[j] = f2bf(v);
        } else if (j < 32768 + 65536) {        // Wt2: [128][512]
            int q = j - 32768;
            int n = q >> 9, k = q & 511;
            float v = (k < 256) ? W3[(size_t)k * 128 + n] : W4[(size_t)(k - 256) * 128 + n];
            Wt2[q] = f2bf(v);
        } else if (j < 98304 + 256) {
            int n = j - 98304; bias1[n] = b1[n] + b2[n];
        } else if (j < 98560 + 128) {
            int n = j - 98560; bias2[n] = b3[n] + b4[n];
        }
    } else if (i < PREP_Z) {
        int j = i - PREP_W1;
        ((int4*)cnt)[j] = make_int4(0, 0, 0, 0);
    }
}

// ---------------------------------------------------------------------------
// histogram + per-edge rank capture (the same atomics the old hist did,
// but the return value now makes the scatter atomic-free)
// ---------------------------------------------------------------------------
__global__ __launch_bounds__(256) void histrank_kernel(
    const int* __restrict__ rows, const int* __restrict__ cols,
    int* __restrict__ rc, int* __restrict__ cc,
    int* __restrict__ rank_r, int* __restrict__ rank_c)
{
    int e = blockIdx.x * 256 + threadIdx.x;
    if (e < NNZE) {
        int r = __builtin_nontemporal_load(rows + e);
        rank_r[e] = atomicAdd(&rc[r], 1);
        int c = __builtin_nontemporal_load(cols + e);
        rank_c[e] = atomicAdd(&cc[c], 1);
    }
}

// ---------------------------------------------------------------------------
// scan phase 1: per-block exclusive scan written directly into rp/cp + totals
// blocks 0..117 rows, 118..235 cols
// ---------------------------------------------------------------------------
#define SCB 118
__global__ __launch_bounds__(256) void scan_local_kernel(
    const int* __restrict__ rc, const int* __restrict__ cc,
    int* __restrict__ rp, int* __restrict__ cp, int* __restrict__ totals)
{
    int b = blockIdx.x;
    const int* cnt = (b < SCB) ? rc : cc;
    int*       esc = (b < SCB) ? rp : cp;
    int lb = (b < SCB) ? b : b - SCB;
    int t = threadIdx.x;
    int idx = lb * 256 + t;

    __shared__ int s[256];
    int v = (idx < NN) ? cnt[idx] : 0;
    s[t] = v;
    __syncthreads();
#pragma unroll
    for (int off = 1; off < 256; off <<= 1) {
        int u = (t >= off) ? s[t - off] : 0;
        __syncthreads();
        s[t] += u;
        __syncthreads();
    }
    if (idx < NN) esc[idx] = s[t] - v;       // exclusive within block
    if (t == 255) totals[b] = s[t];
}

// ---------------------------------------------------------------------------
// scan phase 2+3 merged: each block redundantly scans its side's 118 totals
// in LDS, then adds its offset in place; sets sentinels.
// ---------------------------------------------------------------------------
__global__ __launch_bounds__(256) void scan_addtot_kernel(
    int* __restrict__ rp, int* __restrict__ cp, const int* __restrict__ totals)
{
    int b = blockIdx.x;
    int side = (b >= SCB) ? 1 : 0;
    int lb = side ? b - SCB : b;
    int t = threadIdx.x;

    __shared__ int s[128];
    if (t < 128) s[t] = (t < SCB) ? totals[side * SCB + t] : 0;
    __syncthreads();
#pragma unroll
    for (int off = 1; off < 128; off <<= 1) {
        int u = 0;
        if (t < 128 && t >= off) u = s[t - off];
        __syncthreads();
        if (t < 128) s[t] += u;
        __syncthreads();
    }
    int off = (lb == 0) ? 0 : s[lb - 1];
    int idx = lb * 256 + t;
    int* ptr = side ? cp : rp;
    if (idx < NN) ptr[idx] += off;
    if (b == 0   && t == 0) rp[NN] = NNZE;
    if (b == SCB && t == 0) cp[NN] = NNZE;
}

// ---------------------------------------------------------------------------
// atomic-free, XCD-partitioned scatter: position = ptr[idx] + rank[e].
// Class c writes only rows/cols in its 3750-wide range (clean L2 lines).
// ---------------------------------------------------------------------------
__global__ __launch_bounds__(256) void scatter_rank_kernel(
    const int* __restrict__ rows, const int* __restrict__ cols,
    const float* __restrict__ vals,
    const int* __restrict__ rank_r, const int* __restrict__ rank_c,
    const int* __restrict__ rp, const int* __restrict__ cp,
    int2* __restrict__ csr_pair, int2* __restrict__ csc_pair)
{
    int part = blockIdx.x & (NPART - 1);
    int lo = part * PROWS, hi = lo + PROWS;
    int nb = gridDim.x >> 3;
    int bj = blockIdx.x >> 3;
    int stride = nb * 256;
    for (int e = bj * 256 + threadIdx.x; e < NNZE; e += stride) {
        int r = __builtin_nontemporal_load(rows + e);
        int c = __builtin_nontemporal_load(cols + e);
        float fv = __builtin_nontemporal_load(vals + e);
        int vb = __float_as_int(fv);
        if (r >= lo && r < hi) {
            int p = rp[r] + __builtin_nontemporal_load(rank_r + e);
            csr_pair[p] = make_int2(c, vb);
        }
        if (c >= lo && c < hi) {
            int q = cp[c] + __builtin_nontemporal_load(rank_c + e);
            csc_pair[q] = make_int2(r, vb);
        }
    }
}

// ---------------------------------------------------------------------------
// gather-SpMM D=64: half-wave (32 lanes) per row, lane owns 2 features
// (packed uint of 2 bf16). Unroll-8 for 8 outstanding gathers.
//   acc = sum v*gf[idx]; X = [bf16(acc), bf16(acc*mf[w])]
// ---------------------------------------------------------------------------
__global__ __launch_bounds__(256) void gather64_x_kernel(
    const int* __restrict__ rp, const int2* __restrict__ rpair,
    const int* __restrict__ cp, const int2* __restrict__ cpair,
    const unsigned short* __restrict__ lfb, const unsigned short* __restrict__ rfb,
    unsigned short* __restrict__ X1, unsigned short* __restrict__ X2)
{
    int side = blockIdx.y;
    const int*  ptr  = side ? cp    : rp;
    const int2* pair = side ? cpair : rpair;
    const unsigned int* gf = (const unsigned int*)(side ? lfb : rfb);
    const unsigned int* mf = (const unsigned int*)(side ? rfb : lfb);
    unsigned int* X = (unsigned int*)(side ? X2 : X1);

    int w = blockIdx.x * 8 + (threadIdx.x >> 5);   // half-wave per row
    int l = threadIdx.x & 31;
    int e0 = ptr[w], e1 = ptr[w + 1];
    float a0 = 0.f, a1 = 0.f;
    int e = e0;
    for (; e + 7 < e1; e += 8) {
        int2 p[8];
#pragma unroll
        for (int j = 0; j < 8; ++j) p[j] = nt_pair(&pair[e + j]);
        unsigned int z[8];
#pragma unroll
        for (int j = 0; j < 8; ++j) z[j] = gf[(size_t)p[j].x * 32 + l];
#pragma unroll
        for (int j = 0; j < 8; ++j) {
            float v = __int_as_float(p[j].y);
            a0 += v * bflo(z[j]);
            a1 += v * bfhi(z[j]);
        }
    }
    for (; e < e1; ++e) {
        int2 p0 = nt_pair(&pair[e]);
        unsigned int z0 = gf[(size_t)p0.x * 32 + l];
        float v = __int_as_float(p0.y);
        a0 += v * bflo(z0);
        a1 += v * bfhi(z0);
    }
    unsigned int m = mf[(size_t)w * 32 + l];
    float m0 = a0 * bflo(m);
    float m1 = a1 * bfhi(m);
    X[(size_t)w * 64 + l]      = (unsigned int)f2bf(a0) | ((unsigned int)f2bf(a1) << 16);
    X[(size_t)w * 64 + 32 + l] = (unsigned int)f2bf(m0) | ((unsigned int)f2bf(m1) << 16);
}

// ---------------------------------------------------------------------------
// gather-SpMM D=256, wave-per-row, bf16 z1, unroll-8:
//   acc[0..3] = sum v*z1b[idx]; X3 = [bf16(acc), bf16(acc*y1b[r])]
// ---------------------------------------------------------------------------
__global__ __launch_bounds__(256) void gather256_x_kernel(
    const int* __restrict__ ptr, const int2* __restrict__ pair,
    const unsigned short* __restrict__ z1b, const unsigned short* __restrict__ y1b,
    unsigned short* __restrict__ X3)
{
    int w    = blockIdx.x * 4 + (threadIdx.x >> 6);
    int lane = threadIdx.x & 63;
    int e0 = ptr[w], e1 = ptr[w + 1];
    const ushort4* Z = (const ushort4*)z1b;   // row stride 64 ushort4
    f4 acc = {0.f, 0.f, 0.f, 0.f};
    int e = e0;
    for (; e + 7 < e1; e += 8) {
        int2 p[8];
#pragma unroll
        for (int j = 0; j < 8; ++j) p[j] = nt_pair(&pair[e + j]);
        ushort4 z[8];
#pragma unroll
        for (int j = 0; j < 8; ++j) z[j] = Z[(size_t)p[j].x * 64 + lane];
#pragma unroll
        for (int j = 0; j < 8; ++j) {
            float v = __int_as_float(p[j].y);
            acc[0] += v * bf2f(z[j].x);
            acc[1] += v * bf2f(z[j].y);
            acc[2] += v * bf2f(z[j].z);
            acc[3] += v * bf2f(z[j].w);
        }
    }
    for (; e < e1; ++e) {
        int2 p0 = nt_pair(&pair[e]);
        float v0 = __int_as_float(p0.y);
        ushort4 z0 = Z[(size_t)p0.x * 64 + lane];
        acc[0] += v0 * bf2f(z0.x);
        acc[1] += v0 * bf2f(z0.y);
        acc[2] += v0 * bf2f(z0.z);
        acc[3] += v0 * bf2f(z0.w);
    }
    ushort4 y = ((const ushort4*)y1b)[(size_t)w * 64 + lane];
    ushort4 o0, o1;
    o0.x = f2bf(acc[0]); o0.y = f2bf(acc[1]); o0.z = f2bf(acc[2]); o0.w = f2bf(acc[3]);
    o1.x = f2bf(acc[0] * bf2f(y.x));
    o1.y = f2bf(acc[1] * bf2f(y.y));
    o1.z = f2bf(acc[2] * bf2f(y.z));
    o1.w = f2bf(acc[3] * bf2f(y.w));
    ((ushort4*)X3)[(size_t)w * 128 + lane]      = o0;
    ((ushort4*)X3)[(size_t)w * 128 + 64 + lane] = o1;
}

// ---------------------------------------------------------------------------
// MFMA GEMM: out = relu(X[NN][K] @ Wt^T + bias), Wt [DOUT][K] bf16.
// Dual-input: blockIdx.y selects (Xa->outa) or (Xb->outb), sharing Wt.
// Block: 4 waves, tile 64 rows x DOUT cols. K chunks of 64; LDS XOR-swizzled.
// ---------------------------------------------------------------------------
template<int K, int DOUT, bool OUT_BF16>
__global__ __launch_bounds__(256) void mfma_gemm_kernel(
    const unsigned short* Xa, const unsigned short* Xb,
    const unsigned short* __restrict__ Wt, const float* __restrict__ bias,
    void* outa, void* outb)
{
    constexpr int WC = DOUT / 4;       // cols per wave (64 or 32)
    constexpr int FN = WC / 16;        // 4 or 2
    __shared__ s8 sX[64 * 8];          // [row][chunk], chunk ^= row&7
    __shared__ s8 sW[DOUT * 8];

    const unsigned short* X = blockIdx.y ? Xb : Xa;
    void* outv              = blockIdx.y ? outb : outa;

    const int t       = threadIdx.x;
    const int rowbase = blockIdx.x * 64;
    const int wid     = t >> 6;
    const int lane    = t & 63;
    const int l15     = lane & 15;
    const int kg      = lane >> 4;

    f4 acc[4][FN] = {};

    for (int kc = 0; kc < K; kc += 64) {
#pragma unroll
        for (int it = 0; it < 2; ++it) {
            int ch = t + it * 256;
            int r = ch >> 3, c = ch & 7;
            int row = rowbase + r;
            s8 v = {};
            if (row < NN) v = ((const s8*)X)[((size_t)row * K + kc) / 8 + c];
            sX[(r << 3) | (c ^ (r & 7))] = v;
        }
#pragma unroll
        for (int it = 0; it < DOUT / 32; ++it) {
            int ch = t + it * 256;
            int n = ch >> 3, c = ch & 7;
            sW[(n << 3) | (c ^ (n & 7))] = ((const s8*)Wt)[((size_t)n * K + kc) / 8 + c];
        }
        __syncthreads();

#pragma unroll
        for (int ks = 0; ks < 2; ++ks) {
            int cch = ks * 4 + kg;
            s8 a[4], b[FN];
#pragma unroll
            for (int fm = 0; fm < 4; ++fm) {
                int r0 = fm * 16 + l15;
                a[fm] = sX[(r0 << 3) | (cch ^ (r0 & 7))];
            }
#pragma unroll
            for (int fn = 0; fn < FN; ++fn) {
                int n0 = wid * WC + fn * 16 + l15;
                b[fn] = sW[(n0 << 3) | (cch ^ (n0 & 7))];
            }
#pragma unroll
            for (int fm = 0; fm < 4; ++fm)
#pragma unroll
                for (int fn = 0; fn < FN; ++fn)
                    acc[fm][fn] = __builtin_amdgcn_mfma_f32_16x16x32_bf16(
                        a[fm], b[fn], acc[fm][fn], 0, 0, 0);
        }
        __syncthreads();
    }

    // epilogue: C/D layout col=lane&15, row=kg*4+j
#pragma unroll
    for (int fm = 0; fm < 4; ++fm) {
#pragma unroll
        for (int fn = 0; fn < FN; ++fn) {
            int col = wid * WC + fn * 16 + l15;
            float bv = bias[col];
#pragma unroll
            for (int j = 0; j < 4; ++j) {
                int row = rowbase + fm * 16 + kg * 4 + j;
                if (row < NN) {
                    float v = fmaxf(acc[fm][fn][j] + bv, 0.f);
                    if constexpr (OUT_BF16)
                        ((unsigned short*)outv)[(size_t)row * DOUT + col] = f2bf(v);
                    else
                        ((float*)outv)[(size_t)row * DOUT + col] = v;
                }
            }
        }
    }
}

// ---------------------------------------------------------------------------
extern "C" void kernel_launch(void* const* d_in, const int* in_sizes, int n_in,
                              void* d_out, int out_size, void* d_ws, size_t ws_size,
                              hipStream_t stream)
{
    const float* l_feat = (const float*)d_in[0];
    const float* r_feat = (const float*)d_in[1];
    const int*   rows   = (const int*)  d_in[2];
    const int*   cols   = (const int*)  d_in[3];
    const float* vals   = (const float*)d_in[4];
    const float* W1     = (const float*)d_in[5];
    const float* b1     = (const float*)d_in[6];
    const float* W2     = (const float*)d_in[7];
    const float* b2     = (const float*)d_in[8];
    const float* W3     = (const float*)d_in[9];
    const float* b3     = (const float*)d_in[10];
    const float* W4     = (const float*)d_in[11];
    const float* b4     = (const float*)d_in[12];
    float* out = (float*)d_out;

    // ---- workspace carve ----
    char* p = (char*)d_ws;
    unsigned short* X1  = (unsigned short*)p; p += (size_t)NN * 128 * 2;
    unsigned short* X2  = (unsigned short*)p; p += (size_t)NN * 128 * 2;
    unsigned short* X3  = (unsigned short*)p; p += (size_t)NN * 512 * 2;
    unsigned short* z1b = (unsigned short*)p; p += (size_t)NN * 256 * 2;
    unsigned short* y1b = (unsigned short*)p; p += (size_t)NN * 256 * 2;
    unsigned short* lfb = (unsigned short*)p; p += (size_t)NN * 64 * 2;
    unsigned short* rfb = (unsigned short*)p; p += (size_t)NN * 64 * 2;
    int* row_cnt  = (int*)p; p += (size_t)NN * 4;
    int* col_cnt  = (int*)p; p += (size_t)NN * 4;
    int* totals   = (int*)p; p += 256 * 4;
    unsigned short* Wt1 = (unsigned short*)p; p += 32768 * 2;
    unsigned short* Wt2 = (unsigned short*)p; p += 65536 * 2;
    float* bias1 = (float*)p; p += 256 * 4;
    float* bias2 = (float*)p; p += 128 * 4;
    int*   row_ptr  = (int*)p; p += (size_t)(NN + 4) * 4;
    int*   col_ptr  = (int*)p; p += (size_t)(NN + 4) * 4;
    int2*  csr_pair = (int2*)p; p += (size_t)NNZE * 8;
    int2*  csc_pair = (int2*)p; p += (size_t)NNZE * 8;
    int*   rank_r   = (int*)p; p += (size_t)NNZE * 4;
    int*   rank_c   = (int*)p; p += (size_t)NNZE * 4;

    // 1. fused prep: feats->bf16, weight transpose, bias sums, zero counters
    prep_kernel<<<(PREP_Z + 255) / 256, 256, 0, stream>>>(
        l_feat, r_feat, W1, W2, W3, W4, b1, b2, b3, b4,
        lfb, rfb, Wt1, Wt2, bias1, bias2, row_cnt);

    // 2. histogram + rank capture
    histrank_kernel<<<(NNZE + 255) / 256, 256, 0, stream>>>(
        rows, cols, row_cnt, col_cnt, rank_r, rank_c);

    // 3. hierarchical scan (2 launches)
    scan_local_kernel<<<2 * SCB, 256, 0, stream>>>(row_cnt, col_cnt, row_ptr, col_ptr, totals);
    scan_addtot_kernel<<<2 * SCB, 256, 0, stream>>>(row_ptr, col_ptr, totals);

    // 4. atomic-free XCD-partitioned scatter into CSR + CSC order
    scatter_rank_kernel<<<1024, 256, 0, stream>>>(
        rows, cols, vals, rank_r, rank_c, row_ptr, col_ptr, csr_pair, csc_pair);

    // 5. gather-SpMM D=64, both directions in one launch (half-wave per row)
    {
        dim3 grid(NN / 8, 2);
        gather64_x_kernel<<<grid, 256, 0, stream>>>(
            row_ptr, csr_pair, col_ptr, csc_pair, lfb, rfb, X1, X2);
    }

    // 6. layer-1 MFMA GEMMs, both sides in one launch (shared Wt1)
    {
        dim3 grid((NN + 63) / 64, 2);
        mfma_gemm_kernel<128, 256, true><<<grid, 256, 0, stream>>>(
            X1, X2, Wt1, bias1, y1b, z1b);
    }

    // 7. gather-SpMM D=256 (bf16 z1), fused layer-2 input prep
    gather256_x_kernel<<<NN / 4, 256, 0, stream>>>(row_ptr, csr_pair, z1b, y1b, X3);

    // 8. layer-2 MFMA GEMM -> output (f32)
    {
        dim3 grid((NN + 63) / 64, 1);
        mfma_gemm_kernel<512, 128, false><<<grid, 256, 0, stream>>>(
            X3, X3, Wt2, bias2, out, out);
    }
}

// Round 8
// 198.541 us; speedup vs baseline: 3.7607x; 1.0058x over previous
//
#include <hip/hip_runtime.h>

#define NN     30000
#define NNZE   480000
#define NPART  8
#define PROWS  (NN / NPART)      // 3750, exact
#define NCHUNK 32
#define CH_E   (NNZE / NCHUNK)   // 15000, exact
#define HBIN   (NN / 2)          // 15000 bins per half (60000 B LDS)
#define SCB    118               // ceil(30000/256)

using s8 = __attribute__((ext_vector_type(8))) short;  // 8 bf16 = 4 VGPRs
using f4 = __attribute__((ext_vector_type(4))) float;

__device__ __forceinline__ unsigned short f2bf(float x) {
    unsigned int u = __float_as_uint(x);
    u += 0x7fff + ((u >> 16) & 1);          // round-to-nearest-even
    return (unsigned short)(u >> 16);
}
__device__ __forceinline__ float bf2f(unsigned short h) {
    return __uint_as_float(((unsigned int)h) << 16);
}
__device__ __forceinline__ float bflo(unsigned int z) {
    return __uint_as_float(z << 16);
}
__device__ __forceinline__ float bfhi(unsigned int z) {
    return __uint_as_float(z & 0xffff0000u);
}
__device__ __forceinline__ int2 nt_pair(const int2* p) {
    long long v = __builtin_nontemporal_load((const long long*)p);
    int2 r; r.x = (int)(unsigned int)v; r.y = (int)(v >> 32); return r;
}

// ---------------------------------------------------------------------------
// fused prep: feat->bf16 conversion, weight transpose->bf16, bias sums
// ---------------------------------------------------------------------------
#define FEAT4   (NN * 64 / 4)              // 480000 float4 groups per feat
#define PREP_W0 (2 * FEAT4)                // 960000
#define PREP_W1 (PREP_W0 + 98688)          // wprep range
__global__ __launch_bounds__(256) void prep_kernel(
    const float* __restrict__ lf, const float* __restrict__ rf,
    const float* __restrict__ W1, const float* __restrict__ W2,
    const float* __restrict__ W3, const float* __restrict__ W4,
    const float* __restrict__ b1, const float* __restrict__ b2,
    const float* __restrict__ b3, const float* __restrict__ b4,
    unsigned short* __restrict__ lfb, unsigned short* __restrict__ rfb,
    unsigned short* __restrict__ Wt1, unsigned short* __restrict__ Wt2,
    float* __restrict__ bias1, float* __restrict__ bias2)
{
    int i = blockIdx.x * 256 + threadIdx.x;
    if (i < PREP_W0) {
        const float* src = (i < FEAT4) ? lf : rf;
        unsigned short* dst = (i < FEAT4) ? lfb : rfb;
        int j = (i < FEAT4) ? i : i - FEAT4;
        float4 v = ((const float4*)src)[j];
        ushort4 o;
        o.x = f2bf(v.x); o.y = f2bf(v.y); o.z = f2bf(v.z); o.w = f2bf(v.w);
        ((ushort4*)dst)[j] = o;
    } else if (i < PREP_W1) {
        int j = i - PREP_W0;
        if (j < 32768) {                       // Wt1: [256][128]
            int n = j >> 7, k = j & 127;
            float v = (k < 64) ? W1[(size_t)k * 256 + n] : W2[(size_t)(k - 64) * 256 + n];
            Wt1[j] = f2bf(v);
        } else if (j < 32768 + 65536) {        // Wt2: [128][512]
            int q = j - 32768;
            int n = q >> 9, k = q & 511;
            float v = (k < 256) ? W3[(size_t)k * 128 + n] : W4[(size_t)(k - 256) * 128 + n];
            Wt2[q] = f2bf(v);
        } else if (j < 98304 + 256) {
            int n = j - 98304; bias1[n] = b1[n] + b2[n];
        } else if (j < 98560 + 128) {
            int n = j - 98560; bias2[n] = b3[n] + b4[n];
        }
    }
}

// ---------------------------------------------------------------------------
// LDS-histogram count + local rank (atomic-free at memory side).
// 128 blocks = side(2) x chunk(32) x half(2). Each block: LDS histogram of
// its 15000-bin half over its 15000-edge chunk; rank = LDS atomicAdd return.
// ---------------------------------------------------------------------------
__global__ __launch_bounds__(256) void count_rank_kernel(
    const int* __restrict__ rows, const int* __restrict__ cols,
    int* __restrict__ histP,
    unsigned short* __restrict__ rank_r, unsigned short* __restrict__ rank_c)
{
    int b = blockIdx.x;
    int side  = b >> 6;
    int chunk = (b & 63) >> 1;
    int half  = b & 1;
    const int* keys = side ? cols : rows;
    unsigned short* rank = side ? rank_c : rank_r;
    int binlo = half * HBIN;

    __shared__ int h[HBIN];                  // 60000 B
    for (int i = threadIdx.x; i < HBIN; i += 256) h[i] = 0;
    __syncthreads();

    int e0 = chunk * CH_E;
    for (int e = e0 + threadIdx.x; e < e0 + CH_E; e += 256) {
        int k = __builtin_nontemporal_load(keys + e) - binlo;
        if ((unsigned)k < (unsigned)HBIN)
            rank[e] = (unsigned short)atomicAdd(&h[k], 1);
    }
    __syncthreads();

    int* dst = histP + ((size_t)(side * NCHUNK + chunk)) * NN + binlo;
    for (int i = threadIdx.x; i < HBIN; i += 256)
        __builtin_nontemporal_store(h[i], dst + i);
}

// ---------------------------------------------------------------------------
// scanP: per bin, exclusive prefix over the 32 chunk histograms (in place:
// histP[c][bin] becomes "count of this bin in chunks < c"), then 256-wide
// local scan of the bin totals -> rp/cp (block-local exclusive) + totals.
// ---------------------------------------------------------------------------
__global__ __launch_bounds__(256) void scanP_kernel(
    int* __restrict__ histP,
    int* __restrict__ rp, int* __restrict__ cp, int* __restrict__ totals)
{
    int b = blockIdx.x;
    int side = (b >= SCB) ? 1 : 0;
    int lb = side ? b - SCB : b;
    int t = threadIdx.x;
    int bin = lb * 256 + t;

    int run = 0;
    if (bin < NN) {
        int* base = histP + (size_t)side * NCHUNK * NN + bin;
#pragma unroll 4
        for (int c = 0; c < NCHUNK; ++c) {
            int v = base[(size_t)c * NN];
            base[(size_t)c * NN] = run;
            run += v;
        }
    }
    __shared__ int s[256];
    s[t] = run;
    __syncthreads();
#pragma unroll
    for (int off = 1; off < 256; off <<= 1) {
        int u = (t >= off) ? s[t - off] : 0;
        __syncthreads();
        s[t] += u;
        __syncthreads();
    }
    if (bin < NN) (side ? cp : rp)[bin] = s[t] - run;   // exclusive within block
    if (t == 255) totals[b] = s[t];
}

// ---------------------------------------------------------------------------
// scan phase 2+3 merged: each block redundantly scans its side's 118 totals
// in LDS, then adds its offset in place; sets sentinels.
// ---------------------------------------------------------------------------
__global__ __launch_bounds__(256) void scan_addtot_kernel(
    int* __restrict__ rp, int* __restrict__ cp, const int* __restrict__ totals)
{
    int b = blockIdx.x;
    int side = (b >= SCB) ? 1 : 0;
    int lb = side ? b - SCB : b;
    int t = threadIdx.x;

    __shared__ int s[128];
    if (t < 128) s[t] = (t < SCB) ? totals[side * SCB + t] : 0;
    __syncthreads();
#pragma unroll
    for (int off = 1; off < 128; off <<= 1) {
        int u = 0;
        if (t < 128 && t >= off) u = s[t - off];
        __syncthreads();
        if (t < 128) s[t] += u;
        __syncthreads();
    }
    int off = (lb == 0) ? 0 : s[lb - 1];
    int idx = lb * 256 + t;
    int* ptr = side ? cp : rp;
    if (idx < NN) ptr[idx] += off;
    if (b == 0   && t == 0) rp[NN] = NNZE;
    if (b == SCB && t == 0) cp[NN] = NNZE;
}

// ---------------------------------------------------------------------------
// atomic-free, XCD-partitioned scatter:
//   pos = ptr[key] + P[chunk(e)][key] + rank[e]
// ---------------------------------------------------------------------------
__global__ __launch_bounds__(256) void scatter_rank_kernel(
    const int* __restrict__ rows, const int* __restrict__ cols,
    const float* __restrict__ vals,
    const unsigned short* __restrict__ rank_r, const unsigned short* __restrict__ rank_c,
    const int* __restrict__ histP,
    const int* __restrict__ rp, const int* __restrict__ cp,
    int2* __restrict__ csr_pair, int2* __restrict__ csc_pair)
{
    int part = blockIdx.x & (NPART - 1);
    int lo = part * PROWS, hi = lo + PROWS;
    int nb = gridDim.x >> 3;
    int bj = blockIdx.x >> 3;
    int stride = nb * 256;
    for (int e = bj * 256 + threadIdx.x; e < NNZE; e += stride) {
        int r = __builtin_nontemporal_load(rows + e);
        int c = __builtin_nontemporal_load(cols + e);
        float fv = __builtin_nontemporal_load(vals + e);
        int vb = __float_as_int(fv);
        int chunk = e / CH_E;
        if (r >= lo && r < hi) {
            int p = rp[r] + histP[(size_t)chunk * NN + r]
                  + (int)__builtin_nontemporal_load(rank_r + e);
            csr_pair[p] = make_int2(c, vb);
        }
        if (c >= lo && c < hi) {
            int q = cp[c] + histP[(size_t)(NCHUNK + chunk) * NN + c]
                  + (int)__builtin_nontemporal_load(rank_c + e);
            csc_pair[q] = make_int2(r, vb);
        }
    }
}

// ---------------------------------------------------------------------------
// gather-SpMM D=64: half-wave (32 lanes) per row, lane owns 2 features
// (packed uint of 2 bf16). Unroll-8 for 8 outstanding gathers.
// ---------------------------------------------------------------------------
__global__ __launch_bounds__(256) void gather64_x_kernel(
    const int* __restrict__ rp, const int2* __restrict__ rpair,
    const int* __restrict__ cp, const int2* __restrict__ cpair,
    const unsigned short* __restrict__ lfb, const unsigned short* __restrict__ rfb,
    unsigned short* __restrict__ X1, unsigned short* __restrict__ X2)
{
    int side = blockIdx.y;
    const int*  ptr  = side ? cp    : rp;
    const int2* pair = side ? cpair : rpair;
    const unsigned int* gf = (const unsigned int*)(side ? lfb : rfb);
    const unsigned int* mf = (const unsigned int*)(side ? rfb : lfb);
    unsigned int* X = (unsigned int*)(side ? X2 : X1);

    int w = blockIdx.x * 8 + (threadIdx.x >> 5);   // half-wave per row
    int l = threadIdx.x & 31;
    int e0 = ptr[w], e1 = ptr[w + 1];
    float a0 = 0.f, a1 = 0.f;
    int e = e0;
    for (; e + 7 < e1; e += 8) {
        int2 p[8];
#pragma unroll
        for (int j = 0; j < 8; ++j) p[j] = nt_pair(&pair[e + j]);
        unsigned int z[8];
#pragma unroll
        for (int j = 0; j < 8; ++j) z[j] = gf[(size_t)p[j].x * 32 + l];
#pragma unroll
        for (int j = 0; j < 8; ++j) {
            float v = __int_as_float(p[j].y);
            a0 += v * bflo(z[j]);
            a1 += v * bfhi(z[j]);
        }
    }
    for (; e < e1; ++e) {
        int2 p0 = nt_pair(&pair[e]);
        unsigned int z0 = gf[(size_t)p0.x * 32 + l];
        float v = __int_as_float(p0.y);
        a0 += v * bflo(z0);
        a1 += v * bfhi(z0);
    }
    unsigned int m = mf[(size_t)w * 32 + l];
    float m0 = a0 * bflo(m);
    float m1 = a1 * bfhi(m);
    X[(size_t)w * 64 + l]      = (unsigned int)f2bf(a0) | ((unsigned int)f2bf(a1) << 16);
    X[(size_t)w * 64 + 32 + l] = (unsigned int)f2bf(m0) | ((unsigned int)f2bf(m1) << 16);
}

// ---------------------------------------------------------------------------
// gather-SpMM D=256, wave-per-row, bf16 z1, unroll-8
// ---------------------------------------------------------------------------
__global__ __launch_bounds__(256) void gather256_x_kernel(
    const int* __restrict__ ptr, const int2* __restrict__ pair,
    const unsigned short* __restrict__ z1b, const unsigned short* __restrict__ y1b,
    unsigned short* __restrict__ X3)
{
    int w    = blockIdx.x * 4 + (threadIdx.x >> 6);
    int lane = threadIdx.x & 63;
    int e0 = ptr[w], e1 = ptr[w + 1];
    const ushort4* Z = (const ushort4*)z1b;   // row stride 64 ushort4
    f4 acc = {0.f, 0.f, 0.f, 0.f};
    int e = e0;
    for (; e + 7 < e1; e += 8) {
        int2 p[8];
#pragma unroll
        for (int j = 0; j < 8; ++j) p[j] = nt_pair(&pair[e + j]);
        ushort4 z[8];
#pragma unroll
        for (int j = 0; j < 8; ++j) z[j] = Z[(size_t)p[j].x * 64 + lane];
#pragma unroll
        for (int j = 0; j < 8; ++j) {
            float v = __int_as_float(p[j].y);
            acc[0] += v * bf2f(z[j].x);
            acc[1] += v * bf2f(z[j].y);
            acc[2] += v * bf2f(z[j].z);
            acc[3] += v * bf2f(z[j].w);
        }
    }
    for (; e < e1; ++e) {
        int2 p0 = nt_pair(&pair[e]);
        float v0 = __int_as_float(p0.y);
        ushort4 z0 = Z[(size_t)p0.x * 64 + lane];
        acc[0] += v0 * bf2f(z0.x);
        acc[1] += v0 * bf2f(z0.y);
        acc[2] += v0 * bf2f(z0.z);
        acc[3] += v0 * bf2f(z0.w);
    }
    ushort4 y = ((const ushort4*)y1b)[(size_t)w * 64 + lane];
    ushort4 o0, o1;
    o0.x = f2bf(acc[0]); o0.y = f2bf(acc[1]); o0.z = f2bf(acc[2]); o0.w = f2bf(acc[3]);
    o1.x = f2bf(acc[0] * bf2f(y.x));
    o1.y = f2bf(acc[1] * bf2f(y.y));
    o1.z = f2bf(acc[2] * bf2f(y.z));
    o1.w = f2bf(acc[3] * bf2f(y.w));
    ((ushort4*)X3)[(size_t)w * 128 + lane]      = o0;
    ((ushort4*)X3)[(size_t)w * 128 + 64 + lane] = o1;
}

// ---------------------------------------------------------------------------
// MFMA GEMM: out = relu(X[NN][K] @ Wt^T + bias), Wt [DOUT][K] bf16.
// Dual-input: blockIdx.y selects (Xa->outa) or (Xb->outb), sharing Wt.
// Block: 4 waves, tile 64 rows x DOUT cols. K chunks of 64; LDS XOR-swizzled.
// ---------------------------------------------------------------------------
template<int K, int DOUT, bool OUT_BF16>
__global__ __launch_bounds__(256) void mfma_gemm_kernel(
    const unsigned short* Xa, const unsigned short* Xb,
    const unsigned short* __restrict__ Wt, const float* __restrict__ bias,
    void* outa, void* outb)
{
    constexpr int WC = DOUT / 4;       // cols per wave (64 or 32)
    constexpr int FN = WC / 16;        // 4 or 2
    __shared__ s8 sX[64 * 8];          // [row][chunk], chunk ^= row&7
    __shared__ s8 sW[DOUT * 8];

    const unsigned short* X = blockIdx.y ? Xb : Xa;
    void* outv              = blockIdx.y ? outb : outa;

    const int t       = threadIdx.x;
    const int rowbase = blockIdx.x * 64;
    const int wid     = t >> 6;
    const int lane    = t & 63;
    const int l15     = lane & 15;
    const int kg      = lane >> 4;

    f4 acc[4][FN] = {};

    for (int kc = 0; kc < K; kc += 64) {
#pragma unroll
        for (int it = 0; it < 2; ++it) {
            int ch = t + it * 256;
            int r = ch >> 3, c = ch & 7;
            int row = rowbase + r;
            s8 v = {};
            if (row < NN) v = ((const s8*)X)[((size_t)row * K + kc) / 8 + c];
            sX[(r << 3) | (c ^ (r & 7))] = v;
        }
#pragma unroll
        for (int it = 0; it < DOUT / 32; ++it) {
            int ch = t + it * 256;
            int n = ch >> 3, c = ch & 7;
            sW[(n << 3) | (c ^ (n & 7))] = ((const s8*)Wt)[((size_t)n * K + kc) / 8 + c];
        }
        __syncthreads();

#pragma unroll
        for (int ks = 0; ks < 2; ++ks) {
            int cch = ks * 4 + kg;
            s8 a[4], b[FN];
#pragma unroll
            for (int fm = 0; fm < 4; ++fm) {
                int r0 = fm * 16 + l15;
                a[fm] = sX[(r0 << 3) | (cch ^ (r0 & 7))];
            }
#pragma unroll
            for (int fn = 0; fn < FN; ++fn) {
                int n0 = wid * WC + fn * 16 + l15;
                b[fn] = sW[(n0 << 3) | (cch ^ (n0 & 7))];
            }
#pragma unroll
            for (int fm = 0; fm < 4; ++fm)
#pragma unroll
                for (int fn = 0; fn < FN; ++fn)
                    acc[fm][fn] = __builtin_amdgcn_mfma_f32_16x16x32_bf16(
                        a[fm], b[fn], acc[fm][fn], 0, 0, 0);
        }
        __syncthreads();
    }

    // epilogue: C/D layout col=lane&15, row=kg*4+j
#pragma unroll
    for (int fm = 0; fm < 4; ++fm) {
#pragma unroll
        for (int fn = 0; fn < FN; ++fn) {
            int col = wid * WC + fn * 16 + l15;
            float bv = bias[col];
#pragma unroll
            for (int j = 0; j < 4; ++j) {
                int row = rowbase + fm * 16 + kg * 4 + j;
                if (row < NN) {
                    float v = fmaxf(acc[fm][fn][j] + bv, 0.f);
                    if constexpr (OUT_BF16)
                        ((unsigned short*)outv)[(size_t)row * DOUT + col] = f2bf(v);
                    else
                        ((float*)outv)[(size_t)row * DOUT + col] = v;
                }
            }
        }
    }
}

// ---------------------------------------------------------------------------
extern "C" void kernel_launch(void* const* d_in, const int* in_sizes, int n_in,
                              void* d_out, int out_size, void* d_ws, size_t ws_size,
                              hipStream_t stream)
{
    const float* l_feat = (const float*)d_in[0];
    const float* r_feat = (const float*)d_in[1];
    const int*   rows   = (const int*)  d_in[2];
    const int*   cols   = (const int*)  d_in[3];
    const float* vals   = (const float*)d_in[4];
    const float* W1     = (const float*)d_in[5];
    const float* b1     = (const float*)d_in[6];
    const float* W2     = (const float*)d_in[7];
    const float* b2     = (const float*)d_in[8];
    const float* W3     = (const float*)d_in[9];
    const float* b3     = (const float*)d_in[10];
    const float* W4     = (const float*)d_in[11];
    const float* b4     = (const float*)d_in[12];
    float* out = (float*)d_out;

    // ---- workspace carve ----
    char* p = (char*)d_ws;
    unsigned short* X1  = (unsigned short*)p; p += (size_t)NN * 128 * 2;
    unsigned short* X2  = (unsigned short*)p; p += (size_t)NN * 128 * 2;
    unsigned short* X3  = (unsigned short*)p; p += (size_t)NN * 512 * 2;
    unsigned short* z1b = (unsigned short*)p; p += (size_t)NN * 256 * 2;
    unsigned short* y1b = (unsigned short*)p; p += (size_t)NN * 256 * 2;
    unsigned short* lfb = (unsigned short*)p; p += (size_t)NN * 64 * 2;
    unsigned short* rfb = (unsigned short*)p; p += (size_t)NN * 64 * 2;
    int* histP    = (int*)p; p += (size_t)2 * NCHUNK * NN * 4;   // 7.68 MB
    int* totals   = (int*)p; p += 256 * 4;
    unsigned short* Wt1 = (unsigned short*)p; p += 32768 * 2;
    unsigned short* Wt2 = (unsigned short*)p; p += 65536 * 2;
    float* bias1 = (float*)p; p += 256 * 4;
    float* bias2 = (float*)p; p += 128 * 4;
    int*   row_ptr  = (int*)p; p += (size_t)(NN + 4) * 4;
    int*   col_ptr  = (int*)p; p += (size_t)(NN + 4) * 4;
    int2*  csr_pair = (int2*)p; p += (size_t)NNZE * 8;
    int2*  csc_pair = (int2*)p; p += (size_t)NNZE * 8;
    unsigned short* rank_r = (unsigned short*)p; p += (size_t)NNZE * 2;
    unsigned short* rank_c = (unsigned short*)p; p += (size_t)NNZE * 2;

    // 1. fused prep: feats->bf16, weight transpose, bias sums
    prep_kernel<<<(PREP_W1 + 255) / 256, 256, 0, stream>>>(
        l_feat, r_feat, W1, W2, W3, W4, b1, b2, b3, b4,
        lfb, rfb, Wt1, Wt2, bias1, bias2);

    // 2. LDS-histogram count + local rank (no global atomics)
    count_rank_kernel<<<128, 256, 0, stream>>>(rows, cols, histP, rank_r, rank_c);

    // 3. scan: per-bin chunk prefix (in place) + local bin scan, then totals
    scanP_kernel<<<2 * SCB, 256, 0, stream>>>(histP, row_ptr, col_ptr, totals);
    scan_addtot_kernel<<<2 * SCB, 256, 0, stream>>>(row_ptr, col_ptr, totals);

    // 4. atomic-free XCD-partitioned scatter into CSR + CSC order
    scatter_rank_kernel<<<1024, 256, 0, stream>>>(
        rows, cols, vals, rank_r, rank_c, histP, row_ptr, col_ptr, csr_pair, csc_pair);

    // 5. gather-SpMM D=64, both directions in one launch (half-wave per row)
    {
        dim3 grid(NN / 8, 2);
        gather64_x_kernel<<<grid, 256, 0, stream>>>(
            row_ptr, csr_pair, col_ptr, csc_pair, lfb, rfb, X1, X2);
    }

    // 6. layer-1 MFMA GEMMs, both sides in one launch (shared Wt1)
    {
        dim3 grid((NN + 63) / 64, 2);
        mfma_gemm_kernel<128, 256, true><<<grid, 256, 0, stream>>>(
            X1, X2, Wt1, bias1, y1b, z1b);
    }

    // 7. gather-SpMM D=256 (bf16 z1), fused layer-2 input prep
    gather256_x_kernel<<<NN / 4, 256, 0, stream>>>(row_ptr, csr_pair, z1b, y1b, X3);

    // 8. layer-2 MFMA GEMM -> output (f32)
    {
        dim3 grid((NN + 63) / 64, 1);
        mfma_gemm_kernel<512, 128, false><<<grid, 256, 0, stream>>>(
            X3, X3, Wt2, bias2, out, out);
    }
}